// Round 1
// baseline (1447.225 us; speedup 1.0000x reference)
//
#include <hip/hip_runtime.h>
#include <math.h>

// ---------------- problem constants ----------------
#define Bn_   32
#define Ln_   8192
#define LCn   8184            // L - 8
#define NLn   2
#define NCHn  16              // scan chunks
#define CHn   512             // chunk length (last chunk = 504)

static constexpr long N_BL = (long)Bn_ * LCn;     // 261888

// ws layout (float offsets)
static constexpr long OFF_Z    = 0;               // B*Lc*2
static constexpr long OFF_XIN  = OFF_Z   + 2*N_BL;
static constexpr long OFF_H    = OFF_XIN + 4*N_BL;   // 3 * B*Lc*4
static constexpr long OFF_XC   = OFF_H   + 12*N_BL;  // 3 * B*Lc*4 (doubles as y)
static constexpr long OFF_AP   = OFF_XC  + 12*N_BL;  // 3*32*16*64 = 98304
static constexpr long OFF_SV   = OFF_AP  + 98304;
static constexpr long OFF_RAW  = OFF_SV  + 98304;    // 3 * B*Lc
static constexpr long OFF_SMO  = OFF_RAW + 3*N_BL;   // 3 * B*Lc
static constexpr long OFF_PART = OFF_SMO + 3*N_BL;   // 192 doubles

__device__ __forceinline__ float sp_(float x) {           // softplus = logaddexp(x,0)
    return fmaxf(x, 0.f) + log1pf(expf(-fabsf(x)));
}
__device__ __forceinline__ float si_(float v) {           // silu
    return v / (1.f + expf(-v));
}

// ---------------- 1. deriv + z + x_in ----------------
__global__ void k_prep(const float* __restrict__ x, float* __restrict__ z,
                       float* __restrict__ xin) {
    long idx = (long)blockIdx.x * 256 + threadIdx.x;
    if (idx >= N_BL) return;
    int b = (int)(idx / LCn);
    int t = (int)(idx - (long)b * LCn);
    const float* xb = x + (long)b * Ln_;
    const float c0 = 1.f/280.f, c1 = -4.f/105.f, c2 = 0.2f, c3 = -0.8f,
                c5 = 0.8f, c6 = -0.2f, c7 = 4.f/105.f, c8 = -1.f/280.f;
    float xd  = c0*xb[t]   + c1*xb[t+1] + c2*xb[t+2] + c3*xb[t+3]
              + c5*xb[t+5] + c6*xb[t+6] + c7*xb[t+7] + c8*xb[t+8];
    float z0  = xb[t+4];
    int tf = LCn - 1 - t;
    float xdf = c0*xb[tf]   + c1*xb[tf+1] + c2*xb[tf+2] + c3*xb[tf+3]
              + c5*xb[tf+5] + c6*xb[tf+6] + c7*xb[tf+7] + c8*xb[tf+8];
    float zf0 = xb[tf+4];
    z[idx*2]   = z0;
    z[idx*2+1] = xd;
    float4 v; v.x = z0; v.y = xd; v.z = zf0; v.w = xdf;
    *(float4*)(xin + idx*4) = v;
}

// ---------------- 2. rmsnorm + in_proj(xc half) + causal conv + silu ----------------
__global__ void k_preconv(const float* __restrict__ hin, long mstride, int l,
                          const float* __restrict__ ipw, const float* __restrict__ cw,
                          const float* __restrict__ cbv, const float* __restrict__ nw,
                          float* __restrict__ xc) {
    long idx = (long)blockIdx.x * 256 + threadIdx.x;
    if (idx >= 3*N_BL) return;
    int m = (int)(idx / N_BL);
    long r = idx - (long)m * N_BL;
    int bb = (int)(r / LCn);
    int t  = (int)(r - (long)bb * LCn);
    int ml = m*NLn + l;
    const float* hb = hin + (long)m*mstride + (long)bb*LCn*4;
    const float* W  = ipw + (long)ml*32;      // rows 0..7 of (8,4); we use 0..3
    const float* wn = nw  + ml*4;
    const float* wc = cw  + ml*16;            // [c][j]
    const float* bc = cbv + ml*4;
    float acc0=0.f, acc1=0.f, acc2=0.f, acc3=0.f;
#pragma unroll
    for (int j = 0; j < 4; j++) {
        int tt = t - 3 + j;
        if (tt < 0) continue;
        float4 hv = *(const float4*)(hb + (long)tt*4);
        float ms = (hv.x*hv.x + hv.y*hv.y + hv.z*hv.z + hv.w*hv.w)*0.25f + 1e-5f;
        float rs = 1.f / sqrtf(ms);
        float hn0 = hv.x*rs*wn[0], hn1 = hv.y*rs*wn[1];
        float hn2 = hv.z*rs*wn[2], hn3 = hv.w*rs*wn[3];
        float x0 = W[0]*hn0 + W[1]*hn1 + W[2]*hn2 + W[3]*hn3;
        float x1 = W[4]*hn0 + W[5]*hn1 + W[6]*hn2 + W[7]*hn3;
        float x2 = W[8]*hn0 + W[9]*hn1 + W[10]*hn2 + W[11]*hn3;
        float x3 = W[12]*hn0 + W[13]*hn1 + W[14]*hn2 + W[15]*hn3;
        acc0 = fmaf(x0, wc[0*4+j], acc0);
        acc1 = fmaf(x1, wc[1*4+j], acc1);
        acc2 = fmaf(x2, wc[2*4+j], acc2);
        acc3 = fmaf(x3, wc[3*4+j], acc3);
    }
    float4 o;
    o.x = si_(acc0 + bc[0]); o.y = si_(acc1 + bc[1]);
    o.z = si_(acc2 + bc[2]); o.w = si_(acc3 + bc[3]);
    *(float4*)(xc + (long)m*4*N_BL + r*4) = o;
}

// ---------------- 3a. scan phase B: per-chunk carries ----------------
__global__ void k_scanB(const float* __restrict__ xc, int l,
                        const float* __restrict__ xpw, const float* __restrict__ dtw,
                        const float* __restrict__ dtb, const float* __restrict__ Alog,
                        float* __restrict__ Ap, float* __restrict__ Sv) {
    int wid  = (int)(((long)blockIdx.x * 256 + threadIdx.x) >> 6);
    int lane = threadIdx.x & 63;
    int chunk = wid & (NCHn - 1);
    int bb    = (wid >> 4) & 31;
    int m     = wid >> 9;
    int d = lane >> 4, n = lane & 15;
    int ml = m*NLn + l;
    const float* P = xpw + (long)ml*33*4;
    float p00 = P[0], p01 = P[1], p02 = P[2], p03 = P[3];
    const float* PB = P + (1+n)*4;
    float pb0 = PB[0], pb1 = PB[1], pb2 = PB[2], pb3 = PB[3];
    float Av  = -expf(Alog[((long)ml*4 + d)*16 + n]);
    float dwv = dtw[ml*4 + d];
    float dbv = dtb[ml*4 + d];
    const float* xcb = xc + ((long)m*Bn_ + bb)*LCn*4;
    int t0 = chunk*CHn, t1 = min(t0 + CHn, LCn);
    float ap = 1.f, s = 0.f;
    for (int t = t0; t < t1; t++) {
        float4 u = *(const float4*)(xcb + (long)t*4);
        float dtr   = u.x*p00 + u.y*p01 + u.z*p02 + u.w*p03;
        float delta = sp_(fmaf(dtr, dwv, dbv));
        float a  = expf(delta * Av);
        float Bv = u.x*pb0 + u.y*pb1 + u.z*pb2 + u.w*pb3;
        float ud = (d & 2) ? ((d & 1) ? u.w : u.z) : ((d & 1) ? u.y : u.x);
        float w  = delta * Bv * ud;
        ap *= a;
        s = fmaf(a, s, w);
    }
    long ci = (((long)m*Bn_ + bb)*NCHn + chunk)*64 + lane;
    Ap[ci] = ap; Sv[ci] = s;
}

// ---------------- 3b. scan phase D: prefix carries + final scan + y ----------------
__global__ void k_scanD(float* __restrict__ xc, int l,
                        const float* __restrict__ xpw, const float* __restrict__ dtw,
                        const float* __restrict__ dtb, const float* __restrict__ Alog,
                        const float* __restrict__ Ap, const float* __restrict__ Sv,
                        const float* __restrict__ Dp) {
    int wid  = (int)(((long)blockIdx.x * 256 + threadIdx.x) >> 6);
    int lane = threadIdx.x & 63;
    int chunk = wid & (NCHn - 1);
    int bb    = (wid >> 4) & 31;
    int m     = wid >> 9;
    int d = lane >> 4, n = lane & 15;
    int ml = m*NLn + l;
    const float* P = xpw + (long)ml*33*4;
    float p00 = P[0], p01 = P[1], p02 = P[2], p03 = P[3];
    const float* PB = P + (1+n)*4;
    float pb0 = PB[0], pb1 = PB[1], pb2 = PB[2], pb3 = PB[3];
    const float* PC = P + (17+n)*4;
    float pc0 = PC[0], pc1 = PC[1], pc2 = PC[2], pc3 = PC[3];
    float Av  = -expf(Alog[((long)ml*4 + d)*16 + n]);
    float dwv = dtw[ml*4 + d];
    float dbv = dtb[ml*4 + d];
    float Dd  = Dp[ml*4 + d];
    // fold preceding chunk carries to get h0
    long cb = (((long)m*Bn_ + bb)*NCHn)*64 + lane;
    float hreg = 0.f;
    for (int cc = 0; cc < chunk; cc++) {
        float a = Ap[cb + (long)cc*64];
        float s = Sv[cb + (long)cc*64];
        hreg = fmaf(a, hreg, s);
    }
    float* xcb = xc + ((long)m*Bn_ + bb)*LCn*4;
    int t0 = chunk*CHn, t1 = min(t0 + CHn, LCn);
    for (int t = t0; t < t1; t++) {
        float4 u = *(const float4*)(xcb + (long)t*4);
        float dtr   = u.x*p00 + u.y*p01 + u.z*p02 + u.w*p03;
        float delta = sp_(fmaf(dtr, dwv, dbv));
        float a  = expf(delta * Av);
        float Bv = u.x*pb0 + u.y*pb1 + u.z*pb2 + u.w*pb3;
        float ud = (d & 2) ? ((d & 1) ? u.w : u.z) : ((d & 1) ? u.y : u.x);
        float w  = delta * Bv * ud;
        hreg = fmaf(a, hreg, w);
        float Cv = u.x*pc0 + u.y*pc1 + u.z*pc2 + u.w*pc3;
        float p  = hreg * Cv;
        p += __shfl_xor(p, 1);
        p += __shfl_xor(p, 2);
        p += __shfl_xor(p, 4);
        p += __shfl_xor(p, 8);
        if (n == 0) xcb[(long)t*4 + d] = fmaf(ud, Dd, p);   // y in-place over xc
    }
}

// ---------------- 4. gate + out_proj + residual ----------------
__global__ void k_post(const float* __restrict__ hin, long mstride,
                       float* __restrict__ h, const float* __restrict__ y, int l,
                       const float* __restrict__ ipw, const float* __restrict__ nw,
                       const float* __restrict__ opw) {
    long idx = (long)blockIdx.x * 256 + threadIdx.x;
    if (idx >= 3*N_BL) return;
    int m = (int)(idx / N_BL);
    long r = idx - (long)m * N_BL;
    int ml = m*NLn + l;
    float4 hv = *(const float4*)(hin + (long)m*mstride + r*4);
    float ms = (hv.x*hv.x + hv.y*hv.y + hv.z*hv.z + hv.w*hv.w)*0.25f + 1e-5f;
    float rs = 1.f / sqrtf(ms);
    const float* wn = nw + ml*4;
    float hn0 = hv.x*rs*wn[0], hn1 = hv.y*rs*wn[1];
    float hn2 = hv.z*rs*wn[2], hn3 = hv.w*rs*wn[3];
    const float* W = ipw + (long)(ml*8 + 4)*4;   // rows 4..7 -> res
    float4 yv = *(const float4*)(y + (long)m*4*N_BL + r*4);
    float g0 = yv.x * si_(W[0]*hn0  + W[1]*hn1  + W[2]*hn2  + W[3]*hn3);
    float g1 = yv.y * si_(W[4]*hn0  + W[5]*hn1  + W[6]*hn2  + W[7]*hn3);
    float g2 = yv.z * si_(W[8]*hn0  + W[9]*hn1  + W[10]*hn2 + W[11]*hn3);
    float g3 = yv.w * si_(W[12]*hn0 + W[13]*hn1 + W[14]*hn2 + W[15]*hn3);
    const float* O = opw + ml*16;
    float4 o;
    o.x = O[0]*g0  + O[1]*g1  + O[2]*g2  + O[3]*g3  + hv.x;
    o.y = O[4]*g0  + O[5]*g1  + O[6]*g2  + O[7]*g3  + hv.y;
    o.z = O[8]*g0  + O[9]*g1  + O[10]*g2 + O[11]*g3 + hv.z;
    o.w = O[12]*g0 + O[13]*g1 + O[14]*g2 + O[15]*g3 + hv.w;
    *(float4*)(h + (long)m*4*N_BL + r*4) = o;
}

// ---------------- 5. head: controls + raw omega/gamma/d ----------------
__global__ void k_head(const float* __restrict__ h,
                       const float* __restrict__ ww, const float* __restrict__ wb,
                       const float* __restrict__ gw, const float* __restrict__ gb,
                       const float* __restrict__ dw, const float* __restrict__ dbp,
                       float* __restrict__ raw, float* __restrict__ dout) {
    long idx = (long)blockIdx.x * 256 + threadIdx.x;
    if (idx >= N_BL) return;
    float4 h0 = *(const float4*)(h + idx*4);
    float4 h1 = *(const float4*)(h + 4*N_BL + idx*4);
    float4 h2 = *(const float4*)(h + 8*N_BL + idx*4);
    float4* c = (float4*)(dout + N_BL + idx*12);
    c[0] = h0; c[1] = h1; c[2] = h2;
    raw[idx]          = h0.x*ww[0] + h0.y*ww[1] + h0.z*ww[2] + h0.w*ww[3] + wb[0];
    raw[N_BL + idx]   = (h1.x*gw[0] + h1.y*gw[1] + h1.z*gw[2] + h1.w*gw[3] + gb[0]) / 1000.0f;
    raw[2*N_BL + idx] = fmaxf(h2.x*dw[0] + h2.y*dw[1] + h2.z*dw[2] + h2.w*dw[3] + dbp[0], 0.f);
}

// ---------------- 6. smooth (10-tap, zero-padded) + yhat ----------------
__global__ void k_smooth(const float* __restrict__ raw, const float* __restrict__ z,
                         const float* __restrict__ bp, float* __restrict__ smo,
                         float* __restrict__ dout) {
    long idx = (long)blockIdx.x * 256 + threadIdx.x;
    if (idx >= N_BL) return;
    int b = (int)(idx / LCn);
    int t = (int)(idx - (long)b * LCn);
    const float* ro = raw + (long)b*LCn;
    const float* rg = raw + N_BL   + (long)b*LCn;
    const float* rd = raw + 2*N_BL + (long)b*LCn;
    float so = 0.f, sg = 0.f, sd = 0.f;
    int lo = max(t - 4, 0), hi = min(t + 5, LCn - 1);
    for (int tt = lo; tt <= hi; tt++) {
        so += fabsf(ro[tt]);
        sg += rg[tt];
        sd += fabsf(rd[tt]);
    }
    so *= 0.1f; sg *= 0.1f; sd *= 0.1f;
    smo[idx]          = so;
    smo[N_BL + idx]   = sg;
    smo[2*N_BL + idx] = sd;
    float z1 = z[idx*2];
    float z2 = z[idx*2 + 1] / 0.0001f;
    float bq = fmaxf(bp[0], 0.f) / 1000.0f;
    dout[idx] = -so*so*z1 + sg*z2 - bq*z1*z1*z2 - sd;
}

// ---------------- 7. penalty ----------------
__global__ void k_pen1(const float* __restrict__ smo, double* __restrict__ part) {
    int which = blockIdx.x >> 5;
    int bb    = blockIdx.x & 31;
    const float* s = smo + (long)which*N_BL + (long)bb*LCn;
    double sum = 0.0, sum2 = 0.0;
    for (int t = 1 + threadIdx.x; t < LCn - 1; t += 256) {
        double g = (double)s[t+1] - (double)s[t];
        sum += g; sum2 += g*g;
    }
    __shared__ double s1[256], s2[256];
    s1[threadIdx.x] = sum; s2[threadIdx.x] = sum2;
    __syncthreads();
    for (int o = 128; o > 0; o >>= 1) {
        if ((int)threadIdx.x < o) {
            s1[threadIdx.x] += s1[threadIdx.x + o];
            s2[threadIdx.x] += s2[threadIdx.x + o];
        }
        __syncthreads();
    }
    if (threadIdx.x == 0) {
        part[blockIdx.x*2]     = s1[0];
        part[blockIdx.x*2 + 1] = s2[0];
    }
}

__global__ void k_pen2(const double* __restrict__ part, float* __restrict__ pout) {
    if (threadIdx.x || blockIdx.x) return;
    const double N = (double)(LCn - 2);
    double acc = 0.0;
    for (int w = 0; w < 3; w++) {
        double mv = 0.0;
        for (int bb = 0; bb < 32; bb++) {
            double su  = part[((long)w*32 + bb)*2];
            double s2v = part[((long)w*32 + bb)*2 + 1];
            mv += (s2v - su*su/N) / (N - 1.0);
        }
        acc += mv / 32.0;
    }
    pout[0] = (float)(acc / 3.0);
}

// ---------------- launch ----------------
extern "C" void kernel_launch(void* const* d_in, const int* in_sizes, int n_in,
                              void* d_out, int out_size, void* d_ws, size_t ws_size,
                              hipStream_t stream) {
    const float* x    = (const float*)d_in[0];
    const float* ipw  = (const float*)d_in[1];
    const float* cw   = (const float*)d_in[2];
    const float* cbv  = (const float*)d_in[3];
    const float* xpw  = (const float*)d_in[4];
    const float* dtw  = (const float*)d_in[5];
    const float* dtb  = (const float*)d_in[6];
    const float* Alog = (const float*)d_in[7];
    const float* Dp   = (const float*)d_in[8];
    const float* nw   = (const float*)d_in[9];
    const float* opw  = (const float*)d_in[10];
    const float* ww   = (const float*)d_in[11];
    const float* wb   = (const float*)d_in[12];
    const float* gw   = (const float*)d_in[13];
    const float* gb   = (const float*)d_in[14];
    const float* dw   = (const float*)d_in[15];
    const float* dbp  = (const float*)d_in[16];
    const float* bp   = (const float*)d_in[17];

    float* ws   = (float*)d_ws;
    float* z    = ws + OFF_Z;
    float* xin  = ws + OFF_XIN;
    float* h    = ws + OFF_H;
    float* xc   = ws + OFF_XC;
    float* Ap   = ws + OFF_AP;
    float* Sv   = ws + OFF_SV;
    float* raw  = ws + OFF_RAW;
    float* smo  = ws + OFF_SMO;
    double* part = (double*)(ws + OFF_PART);
    float* dout = (float*)d_out;

    hipLaunchKernelGGL(k_prep, dim3(1023), dim3(256), 0, stream, x, z, xin);
    for (int l = 0; l < NLn; l++) {
        const float* hin = (l == 0) ? xin : h;
        long mstride = (l == 0) ? 0L : 4*N_BL;
        hipLaunchKernelGGL(k_preconv, dim3(3069), dim3(256), 0, stream,
                           hin, mstride, l, ipw, cw, cbv, nw, xc);
        hipLaunchKernelGGL(k_scanB, dim3(384), dim3(256), 0, stream,
                           xc, l, xpw, dtw, dtb, Alog, Ap, Sv);
        hipLaunchKernelGGL(k_scanD, dim3(384), dim3(256), 0, stream,
                           xc, l, xpw, dtw, dtb, Alog, Ap, Sv, Dp);
        hipLaunchKernelGGL(k_post, dim3(3069), dim3(256), 0, stream,
                           hin, mstride, h, xc, l, ipw, nw, opw);
    }
    hipLaunchKernelGGL(k_head, dim3(1023), dim3(256), 0, stream,
                       h, ww, wb, gw, gb, dw, dbp, raw, dout);
    hipLaunchKernelGGL(k_smooth, dim3(1023), dim3(256), 0, stream,
                       raw, z, bp, smo, dout);
    hipLaunchKernelGGL(k_pen1, dim3(96), dim3(256), 0, stream, smo, part);
    hipLaunchKernelGGL(k_pen2, dim3(1), dim3(64), 0, stream, part, dout + 13*N_BL);
}

// Round 2
// 993.519 us; speedup vs baseline: 1.4567x; 1.4567x over previous
//
#include <hip/hip_runtime.h>
#include <math.h>

// ---------------- problem constants ----------------
#define Bn_   32
#define Ln_   8192
#define LCn   8184            // L - 8
#define NLn   2
#define NCHn  64              // scan chunks
#define CHn   128             // chunk length (last chunk = 120)

static constexpr long N_BL = (long)Bn_ * LCn;     // 261888
static constexpr long NCARRY = 3L * Bn_ * NCHn * 64;   // 393216

// ws layout (float offsets)
static constexpr long OFF_Z    = 0;                  // 2N
static constexpr long OFF_XIN  = OFF_Z   + 2*N_BL;   // 4N
static constexpr long OFF_H    = OFF_XIN + 4*N_BL;   // 12N
static constexpr long OFF_XC   = OFF_H   + 12*N_BL;  // 12N
static constexpr long OFF_YB   = OFF_XC  + 12*N_BL;  // 12N
static constexpr long OFF_AP   = OFF_YB  + 12*N_BL;  // NCARRY
static constexpr long OFF_SV   = OFF_AP  + NCARRY;   // NCARRY
static constexpr long OFF_RAW  = OFF_SV  + NCARRY;   // 3N
static constexpr long OFF_SMO  = OFF_RAW + 3*N_BL;   // 3N
static constexpr long OFF_PART = OFF_SMO + 3*N_BL;   // 384 floats (192 doubles)
static constexpr long WS_NEED  = (OFF_PART + 384) * 4;  // bytes

__device__ __forceinline__ float sp_(float x) {           // softplus
    return fmaxf(x, 0.f) + log1pf(expf(-fabsf(x)));
}
__device__ __forceinline__ float si_(float v) {           // silu
    return v / (1.f + expf(-v));
}

// ---------------- 1. deriv + z + x_in ----------------
__global__ void k_prep(const float* __restrict__ x, float* __restrict__ z,
                       float* __restrict__ xin) {
    long idx = (long)blockIdx.x * 256 + threadIdx.x;
    if (idx >= N_BL) return;
    int b = (int)(idx / LCn);
    int t = (int)(idx - (long)b * LCn);
    const float* xb = x + (long)b * Ln_;
    const float c0 = 1.f/280.f, c1 = -4.f/105.f, c2 = 0.2f, c3 = -0.8f,
                c5 = 0.8f, c6 = -0.2f, c7 = 4.f/105.f, c8 = -1.f/280.f;
    float xd  = c0*xb[t]   + c1*xb[t+1] + c2*xb[t+2] + c3*xb[t+3]
              + c5*xb[t+5] + c6*xb[t+6] + c7*xb[t+7] + c8*xb[t+8];
    float z0  = xb[t+4];
    int tf = LCn - 1 - t;
    float xdf = c0*xb[tf]   + c1*xb[tf+1] + c2*xb[tf+2] + c3*xb[tf+3]
              + c5*xb[tf+5] + c6*xb[tf+6] + c7*xb[tf+7] + c8*xb[tf+8];
    float zf0 = xb[tf+4];
    z[idx*2]   = z0;
    z[idx*2+1] = xd;
    float4 v; v.x = z0; v.y = xd; v.z = zf0; v.w = xdf;
    *(float4*)(xin + idx*4) = v;
}

// ---------------- 2. rmsnorm + in_proj(xc half) + causal conv + silu ----------------
__global__ void k_preconv(const float* __restrict__ hin, long mstride, int l,
                          const float* __restrict__ ipw, const float* __restrict__ cw,
                          const float* __restrict__ cbv, const float* __restrict__ nw,
                          float* __restrict__ xc) {
    long idx = (long)blockIdx.x * 256 + threadIdx.x;
    if (idx >= 3*N_BL) return;
    int m = (int)(idx / N_BL);
    long r = idx - (long)m * N_BL;
    int bb = (int)(r / LCn);
    int t  = (int)(r - (long)bb * LCn);
    int ml = m*NLn + l;
    const float* hb = hin + (long)m*mstride + (long)bb*LCn*4;
    const float* W  = ipw + (long)ml*32;
    const float* wn = nw  + ml*4;
    const float* wc = cw  + ml*16;
    const float* bc = cbv + ml*4;
    float acc0=0.f, acc1=0.f, acc2=0.f, acc3=0.f;
#pragma unroll
    for (int j = 0; j < 4; j++) {
        int tt = t - 3 + j;
        if (tt < 0) continue;
        float4 hv = *(const float4*)(hb + (long)tt*4);
        float ms = (hv.x*hv.x + hv.y*hv.y + hv.z*hv.z + hv.w*hv.w)*0.25f + 1e-5f;
        float rs = 1.f / sqrtf(ms);
        float hn0 = hv.x*rs*wn[0], hn1 = hv.y*rs*wn[1];
        float hn2 = hv.z*rs*wn[2], hn3 = hv.w*rs*wn[3];
        float x0 = W[0]*hn0 + W[1]*hn1 + W[2]*hn2 + W[3]*hn3;
        float x1 = W[4]*hn0 + W[5]*hn1 + W[6]*hn2 + W[7]*hn3;
        float x2 = W[8]*hn0 + W[9]*hn1 + W[10]*hn2 + W[11]*hn3;
        float x3 = W[12]*hn0 + W[13]*hn1 + W[14]*hn2 + W[15]*hn3;
        acc0 = fmaf(x0, wc[0*4+j], acc0);
        acc1 = fmaf(x1, wc[1*4+j], acc1);
        acc2 = fmaf(x2, wc[2*4+j], acc2);
        acc3 = fmaf(x3, wc[3*4+j], acc3);
    }
    float4 o;
    o.x = si_(acc0 + bc[0]); o.y = si_(acc1 + bc[1]);
    o.z = si_(acc2 + bc[2]); o.w = si_(acc3 + bc[3]);
    *(float4*)(xc + (long)m*4*N_BL + r*4) = o;
}

// ---------------- 3a. scan phase B: per-chunk carries ----------------
__global__ void k_scanB(const float* __restrict__ xc, int l,
                        const float* __restrict__ xpw, const float* __restrict__ dtw,
                        const float* __restrict__ dtb, const float* __restrict__ Alog,
                        float* __restrict__ Ap, float* __restrict__ Sv) {
    int wid  = (int)(((long)blockIdx.x * 256 + threadIdx.x) >> 6);
    int lane = threadIdx.x & 63;
    int chunk = wid & (NCHn - 1);
    int bb    = (wid >> 6) & 31;
    int m     = wid >> 11;
    int d = lane >> 4, n = lane & 15;
    int ml = m*NLn + l;
    const float* P = xpw + (long)ml*33*4;
    float p00 = P[0], p01 = P[1], p02 = P[2], p03 = P[3];
    const float* PB = P + (1+n)*4;
    float pb0 = PB[0], pb1 = PB[1], pb2 = PB[2], pb3 = PB[3];
    float Av  = -expf(Alog[((long)ml*4 + d)*16 + n]);
    float dwv = dtw[ml*4 + d];
    float dbv = dtb[ml*4 + d];
    const float* xcb = xc + ((long)m*Bn_ + bb)*LCn*4;
    int t0 = chunk*CHn, t1 = min(t0 + CHn, LCn);
    float ap = 1.f, s = 0.f;
#pragma unroll 4
    for (int t = t0; t < t1; t++) {
        float4 u = *(const float4*)(xcb + (long)t*4);
        float dtr   = u.x*p00 + u.y*p01 + u.z*p02 + u.w*p03;
        float delta = sp_(fmaf(dtr, dwv, dbv));
        float a  = expf(delta * Av);
        float Bv = u.x*pb0 + u.y*pb1 + u.z*pb2 + u.w*pb3;
        float ud = (d & 2) ? ((d & 1) ? u.w : u.z) : ((d & 1) ? u.y : u.x);
        float w  = delta * Bv * ud;
        ap *= a;
        s = fmaf(a, s, w);
    }
    long ci = (((long)m*Bn_ + bb)*NCHn + chunk)*64 + lane;
    Ap[ci] = ap; Sv[ci] = s;
}

// ---------------- 3b. scan phase D: prefix carries + final scan + y ----------------
__global__ void k_scanD(const float* __restrict__ xc, float* __restrict__ yb, int l,
                        const float* __restrict__ xpw, const float* __restrict__ dtw,
                        const float* __restrict__ dtb, const float* __restrict__ Alog,
                        const float* __restrict__ Ap, const float* __restrict__ Sv,
                        const float* __restrict__ Dp) {
    int wid  = (int)(((long)blockIdx.x * 256 + threadIdx.x) >> 6);
    int lane = threadIdx.x & 63;
    int chunk = wid & (NCHn - 1);
    int bb    = (wid >> 6) & 31;
    int m     = wid >> 11;
    int d = lane >> 4, n = lane & 15;
    int ml = m*NLn + l;
    const float* P = xpw + (long)ml*33*4;
    float p00 = P[0], p01 = P[1], p02 = P[2], p03 = P[3];
    const float* PB = P + (1+n)*4;
    float pb0 = PB[0], pb1 = PB[1], pb2 = PB[2], pb3 = PB[3];
    const float* PC = P + (17+n)*4;
    float pc0 = PC[0], pc1 = PC[1], pc2 = PC[2], pc3 = PC[3];
    float Av  = -expf(Alog[((long)ml*4 + d)*16 + n]);
    float dwv = dtw[ml*4 + d];
    float dbv = dtb[ml*4 + d];
    float Dd  = Dp[ml*4 + d];
    // fold preceding chunk carries to get h0
    long cb = (((long)m*Bn_ + bb)*NCHn)*64 + lane;
    float hreg = 0.f;
    for (int cc = 0; cc < chunk; cc++) {
        float a = Ap[cb + (long)cc*64];
        float s = Sv[cb + (long)cc*64];
        hreg = fmaf(a, hreg, s);
    }
    const float* xcb = xc + ((long)m*Bn_ + bb)*LCn*4;
    float* ybm = yb + ((long)m*Bn_ + bb)*LCn*4;
    int t0 = chunk*CHn, t1 = min(t0 + CHn, LCn);
#pragma unroll 4
    for (int t = t0; t < t1; t++) {
        float4 u = *(const float4*)(xcb + (long)t*4);
        float dtr   = u.x*p00 + u.y*p01 + u.z*p02 + u.w*p03;
        float delta = sp_(fmaf(dtr, dwv, dbv));
        float a  = expf(delta * Av);
        float Bv = u.x*pb0 + u.y*pb1 + u.z*pb2 + u.w*pb3;
        float ud = (d & 2) ? ((d & 1) ? u.w : u.z) : ((d & 1) ? u.y : u.x);
        float w  = delta * Bv * ud;
        hreg = fmaf(a, hreg, w);
        float Cv = u.x*pc0 + u.y*pc1 + u.z*pc2 + u.w*pc3;
        float p  = hreg * Cv;
        p += __shfl_xor(p, 1);
        p += __shfl_xor(p, 2);
        p += __shfl_xor(p, 4);
        p += __shfl_xor(p, 8);
        if (n == 0) ybm[(long)t*4 + d] = fmaf(ud, Dd, p);
    }
}

// ---------------- 4. gate + out_proj + residual ----------------
__global__ void k_post(const float* __restrict__ hin, long mstride,
                       float* __restrict__ h, const float* __restrict__ y, int l,
                       const float* __restrict__ ipw, const float* __restrict__ nw,
                       const float* __restrict__ opw) {
    long idx = (long)blockIdx.x * 256 + threadIdx.x;
    if (idx >= 3*N_BL) return;
    int m = (int)(idx / N_BL);
    long r = idx - (long)m * N_BL;
    int ml = m*NLn + l;
    float4 hv = *(const float4*)(hin + (long)m*mstride + r*4);
    float ms = (hv.x*hv.x + hv.y*hv.y + hv.z*hv.z + hv.w*hv.w)*0.25f + 1e-5f;
    float rs = 1.f / sqrtf(ms);
    const float* wn = nw + ml*4;
    float hn0 = hv.x*rs*wn[0], hn1 = hv.y*rs*wn[1];
    float hn2 = hv.z*rs*wn[2], hn3 = hv.w*rs*wn[3];
    const float* W = ipw + (long)(ml*8 + 4)*4;
    float4 yv = *(const float4*)(y + (long)m*4*N_BL + r*4);
    float g0 = yv.x * si_(W[0]*hn0  + W[1]*hn1  + W[2]*hn2  + W[3]*hn3);
    float g1 = yv.y * si_(W[4]*hn0  + W[5]*hn1  + W[6]*hn2  + W[7]*hn3);
    float g2 = yv.z * si_(W[8]*hn0  + W[9]*hn1  + W[10]*hn2 + W[11]*hn3);
    float g3 = yv.w * si_(W[12]*hn0 + W[13]*hn1 + W[14]*hn2 + W[15]*hn3);
    const float* O = opw + ml*16;
    float4 o;
    o.x = O[0]*g0  + O[1]*g1  + O[2]*g2  + O[3]*g3  + hv.x;
    o.y = O[4]*g0  + O[5]*g1  + O[6]*g2  + O[7]*g3  + hv.y;
    o.z = O[8]*g0  + O[9]*g1  + O[10]*g2 + O[11]*g3 + hv.z;
    o.w = O[12]*g0 + O[13]*g1 + O[14]*g2 + O[15]*g3 + hv.w;
    *(float4*)(h + (long)m*4*N_BL + r*4) = o;
}

// ---------------- 5. head: controls + raw omega/gamma/d ----------------
__global__ void k_head(const float* __restrict__ h,
                       const float* __restrict__ ww, const float* __restrict__ wb,
                       const float* __restrict__ gw, const float* __restrict__ gb,
                       const float* __restrict__ dw, const float* __restrict__ dbp,
                       float* __restrict__ raw, float* __restrict__ dout) {
    long idx = (long)blockIdx.x * 256 + threadIdx.x;
    if (idx >= N_BL) return;
    float4 h0 = *(const float4*)(h + idx*4);
    float4 h1 = *(const float4*)(h + 4*N_BL + idx*4);
    float4 h2 = *(const float4*)(h + 8*N_BL + idx*4);
    float4* c = (float4*)(dout + N_BL + idx*12);
    c[0] = h0; c[1] = h1; c[2] = h2;
    raw[idx]          = h0.x*ww[0] + h0.y*ww[1] + h0.z*ww[2] + h0.w*ww[3] + wb[0];
    raw[N_BL + idx]   = (h1.x*gw[0] + h1.y*gw[1] + h1.z*gw[2] + h1.w*gw[3] + gb[0]) / 1000.0f;
    raw[2*N_BL + idx] = fmaxf(h2.x*dw[0] + h2.y*dw[1] + h2.z*dw[2] + h2.w*dw[3] + dbp[0], 0.f);
}

// ---------------- 6. smooth (10-tap, zero-padded) + yhat ----------------
__global__ void k_smooth(const float* __restrict__ raw, const float* __restrict__ z,
                         const float* __restrict__ bp, float* __restrict__ smo,
                         float* __restrict__ dout) {
    long idx = (long)blockIdx.x * 256 + threadIdx.x;
    if (idx >= N_BL) return;
    int b = (int)(idx / LCn);
    int t = (int)(idx - (long)b * LCn);
    const float* ro = raw + (long)b*LCn;
    const float* rg = raw + N_BL   + (long)b*LCn;
    const float* rd = raw + 2*N_BL + (long)b*LCn;
    float so = 0.f, sg = 0.f, sd = 0.f;
    int lo = max(t - 4, 0), hi = min(t + 5, LCn - 1);
    for (int tt = lo; tt <= hi; tt++) {
        so += fabsf(ro[tt]);
        sg += rg[tt];
        sd += fabsf(rd[tt]);
    }
    so *= 0.1f; sg *= 0.1f; sd *= 0.1f;
    smo[idx]          = so;
    smo[N_BL + idx]   = sg;
    smo[2*N_BL + idx] = sd;
    float z1 = z[idx*2];
    float z2 = z[idx*2 + 1] / 0.0001f;
    float bq = fmaxf(bp[0], 0.f) / 1000.0f;
    dout[idx] = -so*so*z1 + sg*z2 - bq*z1*z1*z2 - sd;
}

// ---------------- 7. penalty ----------------
__global__ void k_pen1(const float* __restrict__ smo, double* __restrict__ part) {
    int which = blockIdx.x >> 5;
    int bb    = blockIdx.x & 31;
    const float* s = smo + (long)which*N_BL + (long)bb*LCn;
    double sum = 0.0, sum2 = 0.0;
    for (int t = 1 + threadIdx.x; t < LCn - 1; t += 256) {
        double g = (double)s[t+1] - (double)s[t];
        sum += g; sum2 += g*g;
    }
    __shared__ double s1[256], s2[256];
    s1[threadIdx.x] = sum; s2[threadIdx.x] = sum2;
    __syncthreads();
    for (int o = 128; o > 0; o >>= 1) {
        if ((int)threadIdx.x < o) {
            s1[threadIdx.x] += s1[threadIdx.x + o];
            s2[threadIdx.x] += s2[threadIdx.x + o];
        }
        __syncthreads();
    }
    if (threadIdx.x == 0) {
        part[blockIdx.x*2]     = s1[0];
        part[blockIdx.x*2 + 1] = s2[0];
    }
}

__global__ void k_pen2(const double* __restrict__ part, float* __restrict__ pout) {
    if (threadIdx.x || blockIdx.x) return;
    const double N = (double)(LCn - 2);
    double acc = 0.0;
    for (int w = 0; w < 3; w++) {
        double mv = 0.0;
        for (int bb = 0; bb < 32; bb++) {
            double su  = part[((long)w*32 + bb)*2];
            double s2v = part[((long)w*32 + bb)*2 + 1];
            mv += (s2v - su*su/N) / (N - 1.0);
        }
        acc += mv / 32.0;
    }
    pout[0] = (float)(acc / 3.0);
}

// ---------------- launch ----------------
extern "C" void kernel_launch(void* const* d_in, const int* in_sizes, int n_in,
                              void* d_out, int out_size, void* d_ws, size_t ws_size,
                              hipStream_t stream) {
    const float* x    = (const float*)d_in[0];
    const float* ipw  = (const float*)d_in[1];
    const float* cw   = (const float*)d_in[2];
    const float* cbv  = (const float*)d_in[3];
    const float* xpw  = (const float*)d_in[4];
    const float* dtw  = (const float*)d_in[5];
    const float* dtb  = (const float*)d_in[6];
    const float* Alog = (const float*)d_in[7];
    const float* Dp   = (const float*)d_in[8];
    const float* nw   = (const float*)d_in[9];
    const float* opw  = (const float*)d_in[10];
    const float* ww   = (const float*)d_in[11];
    const float* wb   = (const float*)d_in[12];
    const float* gw   = (const float*)d_in[13];
    const float* gb   = (const float*)d_in[14];
    const float* dw   = (const float*)d_in[15];
    const float* dbp  = (const float*)d_in[16];
    const float* bp   = (const float*)d_in[17];

    float* ws   = (float*)d_ws;
    float* z    = ws + OFF_Z;
    float* xin  = ws + OFF_XIN;
    float* h    = ws + OFF_H;
    float* xc   = ws + OFF_XC;
    // y buffer separate from xc (breaks load/store alias serialization in scanD);
    // fall back to in-place if ws is too small.
    float* yb   = ((size_t)WS_NEED <= ws_size) ? (ws + OFF_YB) : xc;
    float* Ap   = ws + OFF_AP;
    float* Sv   = ws + OFF_SV;
    float* raw  = ws + OFF_RAW;
    float* smo  = ws + OFF_SMO;
    double* part = (double*)(ws + OFF_PART);
    float* dout = (float*)d_out;

    hipLaunchKernelGGL(k_prep, dim3(1023), dim3(256), 0, stream, x, z, xin);
    for (int l = 0; l < NLn; l++) {
        const float* hin = (l == 0) ? xin : h;
        long mstride = (l == 0) ? 0L : 4*N_BL;
        hipLaunchKernelGGL(k_preconv, dim3(3069), dim3(256), 0, stream,
                           hin, mstride, l, ipw, cw, cbv, nw, xc);
        hipLaunchKernelGGL(k_scanB, dim3(1536), dim3(256), 0, stream,
                           xc, l, xpw, dtw, dtb, Alog, Ap, Sv);
        hipLaunchKernelGGL(k_scanD, dim3(1536), dim3(256), 0, stream,
                           xc, yb, l, xpw, dtw, dtb, Alog, Ap, Sv, Dp);
        hipLaunchKernelGGL(k_post, dim3(3069), dim3(256), 0, stream,
                           hin, mstride, h, yb, l, ipw, nw, opw);
    }
    hipLaunchKernelGGL(k_head, dim3(1023), dim3(256), 0, stream,
                       h, ww, wb, gw, gb, dw, dbp, raw, dout);
    hipLaunchKernelGGL(k_smooth, dim3(1023), dim3(256), 0, stream,
                       raw, z, bp, smo, dout);
    hipLaunchKernelGGL(k_pen1, dim3(96), dim3(256), 0, stream, smo, part);
    hipLaunchKernelGGL(k_pen2, dim3(1), dim3(64), 0, stream, part, dout + 13*N_BL);
}

// Round 3
// 435.728 us; speedup vs baseline: 3.3214x; 2.2801x over previous
//
#include <hip/hip_runtime.h>
#include <math.h>

// ---------------- problem constants ----------------
#define Bn_   32
#define Ln_   8192
#define LCn   8184            // L - 8
#define NLn   2
#define NCHn  64              // scan chunks
#define CHn   128             // chunk length (last chunk = 120)

static constexpr long N_BL = (long)Bn_ * LCn;     // 261888
static constexpr long NCARRY = 3L * Bn_ * NCHn * 64;   // 393216

// ws layout (float offsets)
static constexpr long OFF_Z    = 0;                  // 2N
static constexpr long OFF_XIN  = OFF_Z   + 2*N_BL;   // 4N
static constexpr long OFF_H    = OFF_XIN + 4*N_BL;   // 12N
static constexpr long OFF_XC   = OFF_H   + 12*N_BL;  // 12N
static constexpr long OFF_YB   = OFF_XC  + 12*N_BL;  // 12N
static constexpr long OFF_AP   = OFF_YB  + 12*N_BL;  // NCARRY
static constexpr long OFF_SV   = OFF_AP  + NCARRY;   // NCARRY
static constexpr long OFF_RAW  = OFF_SV  + NCARRY;   // 3N
static constexpr long OFF_SMO  = OFF_RAW + 3*N_BL;   // 3N
static constexpr long OFF_PART = OFF_SMO + 3*N_BL;   // 384 floats (192 doubles)
static constexpr long WS_NEED  = (OFF_PART + 384) * 4;  // bytes

#define L2E_  1.4426950408889634f     // log2(e)
#define LN2_  0.6931471805599453f     // 1/log2(e)

// fast softplus: log(1+e^x) = max(x,0) + log2(1+2^{-|x|*L2E}) * ln2
__device__ __forceinline__ float sp_(float x) {
    float e = exp2f(-fabsf(x) * L2E_);           // native v_exp_f32
    return fmaxf(x, 0.f) + log2f(1.f + e) * LN2_; // native v_log_f32
}
// fast silu: v / (1 + e^{-v})
__device__ __forceinline__ float si_(float v) {
    float e = exp2f(-v * L2E_);
    return v * __builtin_amdgcn_rcpf(1.f + e);
}

// ---------------- 1. deriv + z + x_in ----------------
__global__ void k_prep(const float* __restrict__ x, float* __restrict__ z,
                       float* __restrict__ xin) {
    long idx = (long)blockIdx.x * 256 + threadIdx.x;
    if (idx >= N_BL) return;
    int b = (int)(idx / LCn);
    int t = (int)(idx - (long)b * LCn);
    const float* xb = x + (long)b * Ln_;
    const float c0 = 1.f/280.f, c1 = -4.f/105.f, c2 = 0.2f, c3 = -0.8f,
                c5 = 0.8f, c6 = -0.2f, c7 = 4.f/105.f, c8 = -1.f/280.f;
    float xd  = c0*xb[t]   + c1*xb[t+1] + c2*xb[t+2] + c3*xb[t+3]
              + c5*xb[t+5] + c6*xb[t+6] + c7*xb[t+7] + c8*xb[t+8];
    float z0  = xb[t+4];
    int tf = LCn - 1 - t;
    float xdf = c0*xb[tf]   + c1*xb[tf+1] + c2*xb[tf+2] + c3*xb[tf+3]
              + c5*xb[tf+5] + c6*xb[tf+6] + c7*xb[tf+7] + c8*xb[tf+8];
    float zf0 = xb[tf+4];
    z[idx*2]   = z0;
    z[idx*2+1] = xd;
    float4 v; v.x = z0; v.y = xd; v.z = zf0; v.w = xdf;
    *(float4*)(xin + idx*4) = v;
}

// ---------------- 2. rmsnorm + in_proj(xc half) + causal conv + silu ----------------
__global__ void k_preconv(const float* __restrict__ hin, long mstride, int l,
                          const float* __restrict__ ipw, const float* __restrict__ cw,
                          const float* __restrict__ cbv, const float* __restrict__ nw,
                          float* __restrict__ xc) {
    long idx = (long)blockIdx.x * 256 + threadIdx.x;
    if (idx >= 3*N_BL) return;
    int m = (int)(idx / N_BL);
    long r = idx - (long)m * N_BL;
    int bb = (int)(r / LCn);
    int t  = (int)(r - (long)bb * LCn);
    int ml = m*NLn + l;
    const float* hb = hin + (long)m*mstride + (long)bb*LCn*4;
    const float* W  = ipw + (long)ml*32;
    const float* wn = nw  + ml*4;
    const float* wc = cw  + ml*16;
    const float* bc = cbv + ml*4;
    float acc0=0.f, acc1=0.f, acc2=0.f, acc3=0.f;
#pragma unroll
    for (int j = 0; j < 4; j++) {
        int tt = t - 3 + j;
        if (tt < 0) continue;
        float4 hv = *(const float4*)(hb + (long)tt*4);
        float ms = (hv.x*hv.x + hv.y*hv.y + hv.z*hv.z + hv.w*hv.w)*0.25f + 1e-5f;
        float rs = __builtin_amdgcn_rsqf(ms);
        float hn0 = hv.x*rs*wn[0], hn1 = hv.y*rs*wn[1];
        float hn2 = hv.z*rs*wn[2], hn3 = hv.w*rs*wn[3];
        float x0 = W[0]*hn0 + W[1]*hn1 + W[2]*hn2 + W[3]*hn3;
        float x1 = W[4]*hn0 + W[5]*hn1 + W[6]*hn2 + W[7]*hn3;
        float x2 = W[8]*hn0 + W[9]*hn1 + W[10]*hn2 + W[11]*hn3;
        float x3 = W[12]*hn0 + W[13]*hn1 + W[14]*hn2 + W[15]*hn3;
        acc0 = fmaf(x0, wc[0*4+j], acc0);
        acc1 = fmaf(x1, wc[1*4+j], acc1);
        acc2 = fmaf(x2, wc[2*4+j], acc2);
        acc3 = fmaf(x3, wc[3*4+j], acc3);
    }
    float4 o;
    o.x = si_(acc0 + bc[0]); o.y = si_(acc1 + bc[1]);
    o.z = si_(acc2 + bc[2]); o.w = si_(acc3 + bc[3]);
    *(float4*)(xc + (long)m*4*N_BL + r*4) = o;
}

// ---------------- 3a. scan phase B: per-chunk carries ----------------
__global__ void k_scanB(const float* __restrict__ xc, int l,
                        const float* __restrict__ xpw, const float* __restrict__ dtw,
                        const float* __restrict__ dtb, const float* __restrict__ Alog,
                        float* __restrict__ Ap, float* __restrict__ Sv) {
    int wid  = (int)(((long)blockIdx.x * 256 + threadIdx.x) >> 6);
    int lane = threadIdx.x & 63;
    int chunk = wid & (NCHn - 1);
    int bb    = (wid >> 6) & 31;
    int m     = wid >> 11;
    int d = lane >> 4, n = lane & 15;
    int ml = m*NLn + l;
    const float* P = xpw + (long)ml*33*4;
    float p00 = P[0], p01 = P[1], p02 = P[2], p03 = P[3];
    const float* PB = P + (1+n)*4;
    float pb0 = PB[0], pb1 = PB[1], pb2 = PB[2], pb3 = PB[3];
    float AvL2 = -exp2f(Alog[((long)ml*4 + d)*16 + n] * L2E_) * L2E_;  // A*log2(e)
    float dwv = dtw[ml*4 + d];
    float dbv = dtb[ml*4 + d];
    const float* xcb = xc + ((long)m*Bn_ + bb)*LCn*4;
    int t0 = chunk*CHn, t1 = min(t0 + CHn, LCn);
    float ap = 1.f, s = 0.f;
#pragma unroll 8
    for (int t = t0; t < t1; t++) {
        float4 u = *(const float4*)(xcb + (long)t*4);
        float dtr   = u.x*p00 + u.y*p01 + u.z*p02 + u.w*p03;
        float delta = sp_(fmaf(dtr, dwv, dbv));
        float a  = exp2f(delta * AvL2);
        float Bv = u.x*pb0 + u.y*pb1 + u.z*pb2 + u.w*pb3;
        float ud = (d & 2) ? ((d & 1) ? u.w : u.z) : ((d & 1) ? u.y : u.x);
        float w  = delta * Bv * ud;
        ap *= a;
        s = fmaf(a, s, w);
    }
    long ci = (((long)m*Bn_ + bb)*NCHn + chunk)*64 + lane;
    Ap[ci] = ap; Sv[ci] = s;
}

// ---------------- 3b. scan phase D: prefix carries + final scan + y ----------------
__global__ void k_scanD(const float* __restrict__ xc, float* __restrict__ yb, int l,
                        const float* __restrict__ xpw, const float* __restrict__ dtw,
                        const float* __restrict__ dtb, const float* __restrict__ Alog,
                        const float* __restrict__ Ap, const float* __restrict__ Sv,
                        const float* __restrict__ Dp) {
    int wid  = (int)(((long)blockIdx.x * 256 + threadIdx.x) >> 6);
    int lane = threadIdx.x & 63;
    int chunk = wid & (NCHn - 1);
    int bb    = (wid >> 6) & 31;
    int m     = wid >> 11;
    int d = lane >> 4, n = lane & 15;
    int ml = m*NLn + l;
    const float* P = xpw + (long)ml*33*4;
    float p00 = P[0], p01 = P[1], p02 = P[2], p03 = P[3];
    const float* PB = P + (1+n)*4;
    float pb0 = PB[0], pb1 = PB[1], pb2 = PB[2], pb3 = PB[3];
    const float* PC = P + (17+n)*4;
    float pc0 = PC[0], pc1 = PC[1], pc2 = PC[2], pc3 = PC[3];
    float AvL2 = -exp2f(Alog[((long)ml*4 + d)*16 + n] * L2E_) * L2E_;
    float dwv = dtw[ml*4 + d];
    float dbv = dtb[ml*4 + d];
    float Dd  = Dp[ml*4 + d];
    // fold preceding chunk carries to get h0
    long cb = (((long)m*Bn_ + bb)*NCHn)*64 + lane;
    float hreg = 0.f;
    for (int cc = 0; cc < chunk; cc++) {
        float a = Ap[cb + (long)cc*64];
        float s = Sv[cb + (long)cc*64];
        hreg = fmaf(a, hreg, s);
    }
    const float* xcb = xc + ((long)m*Bn_ + bb)*LCn*4;
    float* ybm = yb + ((long)m*Bn_ + bb)*LCn*4;
    int t0 = chunk*CHn, t1 = min(t0 + CHn, LCn);
#pragma unroll 4
    for (int t = t0; t < t1; t++) {
        float4 u = *(const float4*)(xcb + (long)t*4);
        float dtr   = u.x*p00 + u.y*p01 + u.z*p02 + u.w*p03;
        float delta = sp_(fmaf(dtr, dwv, dbv));
        float a  = exp2f(delta * AvL2);
        float Bv = u.x*pb0 + u.y*pb1 + u.z*pb2 + u.w*pb3;
        float ud = (d & 2) ? ((d & 1) ? u.w : u.z) : ((d & 1) ? u.y : u.x);
        float w  = delta * Bv * ud;
        hreg = fmaf(a, hreg, w);
        float Cv = u.x*pc0 + u.y*pc1 + u.z*pc2 + u.w*pc3;
        float p  = hreg * Cv;
        p += __shfl_xor(p, 1);
        p += __shfl_xor(p, 2);
        p += __shfl_xor(p, 4);
        p += __shfl_xor(p, 8);
        if (n == 0) ybm[(long)t*4 + d] = fmaf(ud, Dd, p);
    }
}

// ---------------- 4. gate + out_proj + residual ----------------
__global__ void k_post(const float* __restrict__ hin, long mstride,
                       float* __restrict__ h, const float* __restrict__ y, int l,
                       const float* __restrict__ ipw, const float* __restrict__ nw,
                       const float* __restrict__ opw) {
    long idx = (long)blockIdx.x * 256 + threadIdx.x;
    if (idx >= 3*N_BL) return;
    int m = (int)(idx / N_BL);
    long r = idx - (long)m * N_BL;
    int ml = m*NLn + l;
    float4 hv = *(const float4*)(hin + (long)m*mstride + r*4);
    float ms = (hv.x*hv.x + hv.y*hv.y + hv.z*hv.z + hv.w*hv.w)*0.25f + 1e-5f;
    float rs = __builtin_amdgcn_rsqf(ms);
    const float* wn = nw + ml*4;
    float hn0 = hv.x*rs*wn[0], hn1 = hv.y*rs*wn[1];
    float hn2 = hv.z*rs*wn[2], hn3 = hv.w*rs*wn[3];
    const float* W = ipw + (long)(ml*8 + 4)*4;
    float4 yv = *(const float4*)(y + (long)m*4*N_BL + r*4);
    float g0 = yv.x * si_(W[0]*hn0  + W[1]*hn1  + W[2]*hn2  + W[3]*hn3);
    float g1 = yv.y * si_(W[4]*hn0  + W[5]*hn1  + W[6]*hn2  + W[7]*hn3);
    float g2 = yv.z * si_(W[8]*hn0  + W[9]*hn1  + W[10]*hn2 + W[11]*hn3);
    float g3 = yv.w * si_(W[12]*hn0 + W[13]*hn1 + W[14]*hn2 + W[15]*hn3);
    const float* O = opw + ml*16;
    float4 o;
    o.x = O[0]*g0  + O[1]*g1  + O[2]*g2  + O[3]*g3  + hv.x;
    o.y = O[4]*g0  + O[5]*g1  + O[6]*g2  + O[7]*g3  + hv.y;
    o.z = O[8]*g0  + O[9]*g1  + O[10]*g2 + O[11]*g3 + hv.z;
    o.w = O[12]*g0 + O[13]*g1 + O[14]*g2 + O[15]*g3 + hv.w;
    *(float4*)(h + (long)m*4*N_BL + r*4) = o;
}

// ---------------- 5. head: controls + raw omega/gamma/d ----------------
__global__ void k_head(const float* __restrict__ h,
                       const float* __restrict__ ww, const float* __restrict__ wb,
                       const float* __restrict__ gw, const float* __restrict__ gb,
                       const float* __restrict__ dw, const float* __restrict__ dbp,
                       float* __restrict__ raw, float* __restrict__ dout) {
    long idx = (long)blockIdx.x * 256 + threadIdx.x;
    if (idx >= N_BL) return;
    float4 h0 = *(const float4*)(h + idx*4);
    float4 h1 = *(const float4*)(h + 4*N_BL + idx*4);
    float4 h2 = *(const float4*)(h + 8*N_BL + idx*4);
    float4* c = (float4*)(dout + N_BL + idx*12);
    c[0] = h0; c[1] = h1; c[2] = h2;
    raw[idx]          = h0.x*ww[0] + h0.y*ww[1] + h0.z*ww[2] + h0.w*ww[3] + wb[0];
    raw[N_BL + idx]   = (h1.x*gw[0] + h1.y*gw[1] + h1.z*gw[2] + h1.w*gw[3] + gb[0]) / 1000.0f;
    raw[2*N_BL + idx] = fmaxf(h2.x*dw[0] + h2.y*dw[1] + h2.z*dw[2] + h2.w*dw[3] + dbp[0], 0.f);
}

// ---------------- 6. smooth (10-tap, zero-padded) + yhat ----------------
__global__ void k_smooth(const float* __restrict__ raw, const float* __restrict__ z,
                         const float* __restrict__ bp, float* __restrict__ smo,
                         float* __restrict__ dout) {
    long idx = (long)blockIdx.x * 256 + threadIdx.x;
    if (idx >= N_BL) return;
    int b = (int)(idx / LCn);
    int t = (int)(idx - (long)b * LCn);
    const float* ro = raw + (long)b*LCn;
    const float* rg = raw + N_BL   + (long)b*LCn;
    const float* rd = raw + 2*N_BL + (long)b*LCn;
    float so = 0.f, sg = 0.f, sd = 0.f;
    int lo = max(t - 4, 0), hi = min(t + 5, LCn - 1);
    for (int tt = lo; tt <= hi; tt++) {
        so += fabsf(ro[tt]);
        sg += rg[tt];
        sd += fabsf(rd[tt]);
    }
    so *= 0.1f; sg *= 0.1f; sd *= 0.1f;
    smo[idx]          = so;
    smo[N_BL + idx]   = sg;
    smo[2*N_BL + idx] = sd;
    float z1 = z[idx*2];
    float z2 = z[idx*2 + 1] / 0.0001f;
    float bq = fmaxf(bp[0], 0.f) / 1000.0f;
    dout[idx] = -so*so*z1 + sg*z2 - bq*z1*z1*z2 - sd;
}

// ---------------- 7. penalty ----------------
__global__ void k_pen1(const float* __restrict__ smo, double* __restrict__ part) {
    int which = blockIdx.x >> 5;
    int bb    = blockIdx.x & 31;
    const float* s = smo + (long)which*N_BL + (long)bb*LCn;
    double sum = 0.0, sum2 = 0.0;
    for (int t = 1 + threadIdx.x; t < LCn - 1; t += 256) {
        double g = (double)s[t+1] - (double)s[t];
        sum += g; sum2 += g*g;
    }
    __shared__ double s1[256], s2[256];
    s1[threadIdx.x] = sum; s2[threadIdx.x] = sum2;
    __syncthreads();
    for (int o = 128; o > 0; o >>= 1) {
        if ((int)threadIdx.x < o) {
            s1[threadIdx.x] += s1[threadIdx.x + o];
            s2[threadIdx.x] += s2[threadIdx.x + o];
        }
        __syncthreads();
    }
    if (threadIdx.x == 0) {
        part[blockIdx.x*2]     = s1[0];
        part[blockIdx.x*2 + 1] = s2[0];
    }
}

__global__ void k_pen2(const double* __restrict__ part, float* __restrict__ pout) {
    if (threadIdx.x || blockIdx.x) return;
    const double N = (double)(LCn - 2);
    double acc = 0.0;
    for (int w = 0; w < 3; w++) {
        double mv = 0.0;
        for (int bb = 0; bb < 32; bb++) {
            double su  = part[((long)w*32 + bb)*2];
            double s2v = part[((long)w*32 + bb)*2 + 1];
            mv += (s2v - su*su/N) / (N - 1.0);
        }
        acc += mv / 32.0;
    }
    pout[0] = (float)(acc / 3.0);
}

// ---------------- launch ----------------
extern "C" void kernel_launch(void* const* d_in, const int* in_sizes, int n_in,
                              void* d_out, int out_size, void* d_ws, size_t ws_size,
                              hipStream_t stream) {
    const float* x    = (const float*)d_in[0];
    const float* ipw  = (const float*)d_in[1];
    const float* cw   = (const float*)d_in[2];
    const float* cbv  = (const float*)d_in[3];
    const float* xpw  = (const float*)d_in[4];
    const float* dtw  = (const float*)d_in[5];
    const float* dtb  = (const float*)d_in[6];
    const float* Alog = (const float*)d_in[7];
    const float* Dp   = (const float*)d_in[8];
    const float* nw   = (const float*)d_in[9];
    const float* opw  = (const float*)d_in[10];
    const float* ww   = (const float*)d_in[11];
    const float* wb   = (const float*)d_in[12];
    const float* gw   = (const float*)d_in[13];
    const float* gb   = (const float*)d_in[14];
    const float* dw   = (const float*)d_in[15];
    const float* dbp  = (const float*)d_in[16];
    const float* bp   = (const float*)d_in[17];

    float* ws   = (float*)d_ws;
    float* z    = ws + OFF_Z;
    float* xin  = ws + OFF_XIN;
    float* h    = ws + OFF_H;
    float* xc   = ws + OFF_XC;
    float* yb   = ((size_t)WS_NEED <= ws_size) ? (ws + OFF_YB) : xc;
    float* Ap   = ws + OFF_AP;
    float* Sv   = ws + OFF_SV;
    float* raw  = ws + OFF_RAW;
    float* smo  = ws + OFF_SMO;
    double* part = (double*)(ws + OFF_PART);
    float* dout = (float*)d_out;

    hipLaunchKernelGGL(k_prep, dim3(1023), dim3(256), 0, stream, x, z, xin);
    for (int l = 0; l < NLn; l++) {
        const float* hin = (l == 0) ? xin : h;
        long mstride = (l == 0) ? 0L : 4*N_BL;
        hipLaunchKernelGGL(k_preconv, dim3(3069), dim3(256), 0, stream,
                           hin, mstride, l, ipw, cw, cbv, nw, xc);
        hipLaunchKernelGGL(k_scanB, dim3(1536), dim3(256), 0, stream,
                           xc, l, xpw, dtw, dtb, Alog, Ap, Sv);
        hipLaunchKernelGGL(k_scanD, dim3(1536), dim3(256), 0, stream,
                           xc, yb, l, xpw, dtw, dtb, Alog, Ap, Sv, Dp);
        hipLaunchKernelGGL(k_post, dim3(3069), dim3(256), 0, stream,
                           hin, mstride, h, yb, l, ipw, nw, opw);
    }
    hipLaunchKernelGGL(k_head, dim3(1023), dim3(256), 0, stream,
                       h, ww, wb, gw, gb, dw, dbp, raw, dout);
    hipLaunchKernelGGL(k_smooth, dim3(1023), dim3(256), 0, stream,
                       raw, z, bp, smo, dout);
    hipLaunchKernelGGL(k_pen1, dim3(96), dim3(256), 0, stream, smo, part);
    hipLaunchKernelGGL(k_pen2, dim3(1), dim3(64), 0, stream, part, dout + 13*N_BL);
}

// Round 4
// 357.205 us; speedup vs baseline: 4.0515x; 1.2198x over previous
//
#include <hip/hip_runtime.h>
#include <math.h>

// ---------------- problem constants ----------------
#define Bn_   32
#define Ln_   8192
#define LCn   8184            // L - 8
#define NLn   2
#define NCHn  128             // scan chunks
#define CHn   64              // chunk length (last chunk = 56)

static constexpr long N_BL = (long)Bn_ * LCn;            // 261888
static constexpr long NCARRY = 3L * Bn_ * NCHn * 64;     // 786432

// ws layout (float offsets)
static constexpr long OFF_Z    = 0;                  // 2N
static constexpr long OFF_XIN  = OFF_Z   + 2*N_BL;   // 4N
static constexpr long OFF_H    = OFF_XIN + 4*N_BL;   // 12N
static constexpr long OFF_XC   = OFF_H   + 12*N_BL;  // 12N
static constexpr long OFF_YB   = OFF_XC  + 12*N_BL;  // 12N
static constexpr long OFF_AP   = OFF_YB  + 12*N_BL;  // NCARRY
static constexpr long OFF_SV   = OFF_AP  + NCARRY;   // NCARRY (becomes H0 after scanC)
// raw/smo/part alias the Ap/Sv region (dead after the last scanD)
static constexpr long OFF_RAW  = OFF_AP;             // 3N
static constexpr long OFF_SMO  = OFF_AP + 3*N_BL;    // 3N
static constexpr long OFF_PART = OFF_AP + 6*N_BL;    // 384 floats (192 doubles)
static constexpr long WS_NEED  = (OFF_SV + NCARRY) * 4;  // bytes

#define L2E_  1.4426950408889634f     // log2(e)
#define LN2_  0.6931471805599453f     // ln(2)
#define EXP2_(x) __builtin_amdgcn_exp2f(x)
#define LOG2_(x) __builtin_amdgcn_logf(x)

// fast silu: v / (1 + e^{-v})
__device__ __forceinline__ float si_(float v) {
    float e = EXP2_(-v * L2E_);
    return v * __builtin_amdgcn_rcpf(1.f + e);
}

// ---------------- 1. deriv + z + x_in ----------------
__global__ void k_prep(const float* __restrict__ x, float* __restrict__ z,
                       float* __restrict__ xin) {
    long idx = (long)blockIdx.x * 256 + threadIdx.x;
    if (idx >= N_BL) return;
    int b = (int)(idx / LCn);
    int t = (int)(idx - (long)b * LCn);
    const float* xb = x + (long)b * Ln_;
    const float c0 = 1.f/280.f, c1 = -4.f/105.f, c2 = 0.2f, c3 = -0.8f,
                c5 = 0.8f, c6 = -0.2f, c7 = 4.f/105.f, c8 = -1.f/280.f;
    float xd  = c0*xb[t]   + c1*xb[t+1] + c2*xb[t+2] + c3*xb[t+3]
              + c5*xb[t+5] + c6*xb[t+6] + c7*xb[t+7] + c8*xb[t+8];
    float z0  = xb[t+4];
    int tf = LCn - 1 - t;
    float xdf = c0*xb[tf]   + c1*xb[tf+1] + c2*xb[tf+2] + c3*xb[tf+3]
              + c5*xb[tf+5] + c6*xb[tf+6] + c7*xb[tf+7] + c8*xb[tf+8];
    float zf0 = xb[tf+4];
    z[idx*2]   = z0;
    z[idx*2+1] = xd;
    float4 v; v.x = z0; v.y = xd; v.z = zf0; v.w = xdf;
    *(float4*)(xin + idx*4) = v;
}

// ---------------- 2. rmsnorm + in_proj(xc half) + causal conv + silu ----------------
__global__ void k_preconv(const float* __restrict__ hin, long mstride, int l,
                          const float* __restrict__ ipw, const float* __restrict__ cw,
                          const float* __restrict__ cbv, const float* __restrict__ nw,
                          float* __restrict__ xc) {
    long idx = (long)blockIdx.x * 256 + threadIdx.x;
    if (idx >= 3*N_BL) return;
    int m = (int)(idx / N_BL);
    long r = idx - (long)m * N_BL;
    int bb = (int)(r / LCn);
    int t  = (int)(r - (long)bb * LCn);
    int ml = m*NLn + l;
    const float* hb = hin + (long)m*mstride + (long)bb*LCn*4;
    const float* W  = ipw + (long)ml*32;
    const float* wn = nw  + ml*4;
    const float* wc = cw  + ml*16;
    const float* bc = cbv + ml*4;
    float acc0=0.f, acc1=0.f, acc2=0.f, acc3=0.f;
#pragma unroll
    for (int j = 0; j < 4; j++) {
        int tt = t - 3 + j;
        if (tt < 0) continue;
        float4 hv = *(const float4*)(hb + (long)tt*4);
        float ms = (hv.x*hv.x + hv.y*hv.y + hv.z*hv.z + hv.w*hv.w)*0.25f + 1e-5f;
        float rs = __builtin_amdgcn_rsqf(ms);
        float hn0 = hv.x*rs*wn[0], hn1 = hv.y*rs*wn[1];
        float hn2 = hv.z*rs*wn[2], hn3 = hv.w*rs*wn[3];
        float x0 = W[0]*hn0 + W[1]*hn1 + W[2]*hn2 + W[3]*hn3;
        float x1 = W[4]*hn0 + W[5]*hn1 + W[6]*hn2 + W[7]*hn3;
        float x2 = W[8]*hn0 + W[9]*hn1 + W[10]*hn2 + W[11]*hn3;
        float x3 = W[12]*hn0 + W[13]*hn1 + W[14]*hn2 + W[15]*hn3;
        acc0 = fmaf(x0, wc[0*4+j], acc0);
        acc1 = fmaf(x1, wc[1*4+j], acc1);
        acc2 = fmaf(x2, wc[2*4+j], acc2);
        acc3 = fmaf(x3, wc[3*4+j], acc3);
    }
    float4 o;
    o.x = si_(acc0 + bc[0]); o.y = si_(acc1 + bc[1]);
    o.z = si_(acc2 + bc[2]); o.w = si_(acc3 + bc[3]);
    *(float4*)(xc + (long)m*4*N_BL + r*4) = o;
}

// ---------------- 3a. scan phase B: per-chunk carries ----------------
__global__ void k_scanB(const float* __restrict__ xc, int l,
                        const float* __restrict__ xpw, const float* __restrict__ dtw,
                        const float* __restrict__ dtb, const float* __restrict__ Alog,
                        float* __restrict__ Ap, float* __restrict__ Sv) {
    int wid  = (int)(((long)blockIdx.x * 256 + threadIdx.x) >> 6);
    int lane = threadIdx.x & 63;
    int chunk = wid & (NCHn - 1);
    int bb    = (wid >> 7) & 31;
    int m     = wid >> 12;
    int d = lane >> 4, n = lane & 15;
    int ml = m*NLn + l;
    const float* P = xpw + (long)ml*33*4;
    float p00 = P[0], p01 = P[1], p02 = P[2], p03 = P[3];
    const float* PB = P + (1+n)*4;
    float pb0 = PB[0], pb1 = PB[1], pb2 = PB[2], pb3 = PB[3];
    float AvP = -expf(Alog[((long)ml*4 + d)*16 + n]);   // plain A (<0)
    float dwv = dtw[ml*4 + d];
    float dbv = dtb[ml*4 + d];
    const float* xcb = xc + ((long)m*Bn_ + bb)*LCn*4;
    int t0 = chunk*CHn, t1 = min(t0 + CHn, LCn);
    float ap = 1.f, s = 0.f;
#pragma unroll 8
    for (int t = t0; t < t1; t++) {
        float4 u = *(const float4*)(xcb + (long)t*4);
        float dtr   = u.x*p00 + u.y*p01 + u.z*p02 + u.w*p03;
        float zt    = fmaf(dtr, dwv, dbv);
        float lg    = LOG2_(1.f + EXP2_(zt * L2E_));   // log2(1+e^z)
        float delta = lg * LN2_;
        float a     = EXP2_(lg * AvP);                 // (1+e^z)^A
        float Bv = u.x*pb0 + u.y*pb1 + u.z*pb2 + u.w*pb3;
        float ud = (d & 2) ? ((d & 1) ? u.w : u.z) : ((d & 1) ? u.y : u.x);
        float w  = delta * Bv * ud;
        ap *= a;
        s = fmaf(a, s, w);
    }
    long ci = (((long)m*Bn_ + bb)*NCHn + chunk)*64 + lane;
    Ap[ci] = ap; Sv[ci] = s;
}

// ---------------- 3b. scan phase C: chunk carries -> exclusive prefix h0 (in place over Sv) ----------------
__global__ void k_scanC(const float* __restrict__ Ap, float* __restrict__ Sv) {
    int wid  = (int)(((long)blockIdx.x * 256 + threadIdx.x) >> 6);
    int lane = threadIdx.x & 63;
    int bb = wid & 31;
    int m  = wid >> 5;
    long base = (((long)m*Bn_ + bb)*NCHn)*64 + lane;
    float h = 0.f;
#pragma unroll 4
    for (int cc = 0; cc < NCHn; cc++) {
        long ci = base + (long)cc*64;
        float a = Ap[ci];
        float s = Sv[ci];
        Sv[ci] = h;               // exclusive prefix: h0 for chunk cc
        h = fmaf(a, h, s);
    }
}

// ---------------- 3c. scan phase D: final scan + y ----------------
__global__ void k_scanD(const float* __restrict__ xc, float* __restrict__ yb, int l,
                        const float* __restrict__ xpw, const float* __restrict__ dtw,
                        const float* __restrict__ dtb, const float* __restrict__ Alog,
                        const float* __restrict__ H0, const float* __restrict__ Dp) {
    int wid  = (int)(((long)blockIdx.x * 256 + threadIdx.x) >> 6);
    int lane = threadIdx.x & 63;
    int chunk = wid & (NCHn - 1);
    int bb    = (wid >> 7) & 31;
    int m     = wid >> 12;
    int d = lane >> 4, n = lane & 15;
    int ml = m*NLn + l;
    const float* P = xpw + (long)ml*33*4;
    float p00 = P[0], p01 = P[1], p02 = P[2], p03 = P[3];
    const float* PB = P + (1+n)*4;
    float pb0 = PB[0], pb1 = PB[1], pb2 = PB[2], pb3 = PB[3];
    const float* PC = P + (17+n)*4;
    float pc0 = PC[0], pc1 = PC[1], pc2 = PC[2], pc3 = PC[3];
    float AvP = -expf(Alog[((long)ml*4 + d)*16 + n]);
    float dwv = dtw[ml*4 + d];
    float dbv = dtb[ml*4 + d];
    float Dd  = Dp[ml*4 + d];
    float hreg = H0[(((long)m*Bn_ + bb)*NCHn + chunk)*64 + lane];
    const float* xcb = xc + ((long)m*Bn_ + bb)*LCn*4;
    float* ybm = yb + ((long)m*Bn_ + bb)*LCn*4;
    int t0 = chunk*CHn, t1 = min(t0 + CHn, LCn);
#pragma unroll 4
    for (int t = t0; t < t1; t++) {
        float4 u = *(const float4*)(xcb + (long)t*4);
        float dtr   = u.x*p00 + u.y*p01 + u.z*p02 + u.w*p03;
        float zt    = fmaf(dtr, dwv, dbv);
        float lg    = LOG2_(1.f + EXP2_(zt * L2E_));
        float delta = lg * LN2_;
        float a     = EXP2_(lg * AvP);
        float Bv = u.x*pb0 + u.y*pb1 + u.z*pb2 + u.w*pb3;
        float ud = (d & 2) ? ((d & 1) ? u.w : u.z) : ((d & 1) ? u.y : u.x);
        float w  = delta * Bv * ud;
        hreg = fmaf(a, hreg, w);
        float Cv = u.x*pc0 + u.y*pc1 + u.z*pc2 + u.w*pc3;
        float p  = hreg * Cv;
        p += __shfl_xor(p, 1);
        p += __shfl_xor(p, 2);
        p += __shfl_xor(p, 4);
        p += __shfl_xor(p, 8);
        if (n == 0) ybm[(long)t*4 + d] = fmaf(ud, Dd, p);
    }
}

// ---------------- 4. gate + out_proj + residual ----------------
__global__ void k_post(const float* __restrict__ hin, long mstride,
                       float* __restrict__ h, const float* __restrict__ y, int l,
                       const float* __restrict__ ipw, const float* __restrict__ nw,
                       const float* __restrict__ opw) {
    long idx = (long)blockIdx.x * 256 + threadIdx.x;
    if (idx >= 3*N_BL) return;
    int m = (int)(idx / N_BL);
    long r = idx - (long)m * N_BL;
    int ml = m*NLn + l;
    float4 hv = *(const float4*)(hin + (long)m*mstride + r*4);
    float ms = (hv.x*hv.x + hv.y*hv.y + hv.z*hv.z + hv.w*hv.w)*0.25f + 1e-5f;
    float rs = __builtin_amdgcn_rsqf(ms);
    const float* wn = nw + ml*4;
    float hn0 = hv.x*rs*wn[0], hn1 = hv.y*rs*wn[1];
    float hn2 = hv.z*rs*wn[2], hn3 = hv.w*rs*wn[3];
    const float* W = ipw + (long)(ml*8 + 4)*4;
    float4 yv = *(const float4*)(y + (long)m*4*N_BL + r*4);
    float g0 = yv.x * si_(W[0]*hn0  + W[1]*hn1  + W[2]*hn2  + W[3]*hn3);
    float g1 = yv.y * si_(W[4]*hn0  + W[5]*hn1  + W[6]*hn2  + W[7]*hn3);
    float g2 = yv.z * si_(W[8]*hn0  + W[9]*hn1  + W[10]*hn2 + W[11]*hn3);
    float g3 = yv.w * si_(W[12]*hn0 + W[13]*hn1 + W[14]*hn2 + W[15]*hn3);
    const float* O = opw + ml*16;
    float4 o;
    o.x = O[0]*g0  + O[1]*g1  + O[2]*g2  + O[3]*g3  + hv.x;
    o.y = O[4]*g0  + O[5]*g1  + O[6]*g2  + O[7]*g3  + hv.y;
    o.z = O[8]*g0  + O[9]*g1  + O[10]*g2 + O[11]*g3 + hv.z;
    o.w = O[12]*g0 + O[13]*g1 + O[14]*g2 + O[15]*g3 + hv.w;
    *(float4*)(h + (long)m*4*N_BL + r*4) = o;
}

// ---------------- 5. head: controls + raw omega/gamma/d ----------------
__global__ void k_head(const float* __restrict__ h,
                       const float* __restrict__ ww, const float* __restrict__ wb,
                       const float* __restrict__ gw, const float* __restrict__ gb,
                       const float* __restrict__ dw, const float* __restrict__ dbp,
                       float* __restrict__ raw, float* __restrict__ dout) {
    long idx = (long)blockIdx.x * 256 + threadIdx.x;
    if (idx >= N_BL) return;
    float4 h0 = *(const float4*)(h + idx*4);
    float4 h1 = *(const float4*)(h + 4*N_BL + idx*4);
    float4 h2 = *(const float4*)(h + 8*N_BL + idx*4);
    float4* c = (float4*)(dout + N_BL + idx*12);
    c[0] = h0; c[1] = h1; c[2] = h2;
    raw[idx]          = h0.x*ww[0] + h0.y*ww[1] + h0.z*ww[2] + h0.w*ww[3] + wb[0];
    raw[N_BL + idx]   = (h1.x*gw[0] + h1.y*gw[1] + h1.z*gw[2] + h1.w*gw[3] + gb[0]) / 1000.0f;
    raw[2*N_BL + idx] = fmaxf(h2.x*dw[0] + h2.y*dw[1] + h2.z*dw[2] + h2.w*dw[3] + dbp[0], 0.f);
}

// ---------------- 6. smooth (10-tap, zero-padded) + yhat ----------------
__global__ void k_smooth(const float* __restrict__ raw, const float* __restrict__ z,
                         const float* __restrict__ bp, float* __restrict__ smo,
                         float* __restrict__ dout) {
    long idx = (long)blockIdx.x * 256 + threadIdx.x;
    if (idx >= N_BL) return;
    int b = (int)(idx / LCn);
    int t = (int)(idx - (long)b * LCn);
    const float* ro = raw + (long)b*LCn;
    const float* rg = raw + N_BL   + (long)b*LCn;
    const float* rd = raw + 2*N_BL + (long)b*LCn;
    float so = 0.f, sg = 0.f, sd = 0.f;
    int lo = max(t - 4, 0), hi = min(t + 5, LCn - 1);
    for (int tt = lo; tt <= hi; tt++) {
        so += fabsf(ro[tt]);
        sg += rg[tt];
        sd += fabsf(rd[tt]);
    }
    so *= 0.1f; sg *= 0.1f; sd *= 0.1f;
    smo[idx]          = so;
    smo[N_BL + idx]   = sg;
    smo[2*N_BL + idx] = sd;
    float z1 = z[idx*2];
    float z2 = z[idx*2 + 1] / 0.0001f;
    float bq = fmaxf(bp[0], 0.f) / 1000.0f;
    dout[idx] = -so*so*z1 + sg*z2 - bq*z1*z1*z2 - sd;
}

// ---------------- 7. penalty ----------------
__global__ void k_pen1(const float* __restrict__ smo, double* __restrict__ part) {
    int which = blockIdx.x >> 5;
    int bb    = blockIdx.x & 31;
    const float* s = smo + (long)which*N_BL + (long)bb*LCn;
    double sum = 0.0, sum2 = 0.0;
    for (int t = 1 + threadIdx.x; t < LCn - 1; t += 256) {
        double g = (double)s[t+1] - (double)s[t];
        sum += g; sum2 += g*g;
    }
    __shared__ double s1[256], s2[256];
    s1[threadIdx.x] = sum; s2[threadIdx.x] = sum2;
    __syncthreads();
    for (int o = 128; o > 0; o >>= 1) {
        if ((int)threadIdx.x < o) {
            s1[threadIdx.x] += s1[threadIdx.x + o];
            s2[threadIdx.x] += s2[threadIdx.x + o];
        }
        __syncthreads();
    }
    if (threadIdx.x == 0) {
        part[blockIdx.x*2]     = s1[0];
        part[blockIdx.x*2 + 1] = s2[0];
    }
}

__global__ void k_pen2(const double* __restrict__ part, float* __restrict__ pout) {
    if (threadIdx.x || blockIdx.x) return;
    const double N = (double)(LCn - 2);
    double acc = 0.0;
    for (int w = 0; w < 3; w++) {
        double mv = 0.0;
        for (int bb = 0; bb < 32; bb++) {
            double su  = part[((long)w*32 + bb)*2];
            double s2v = part[((long)w*32 + bb)*2 + 1];
            mv += (s2v - su*su/N) / (N - 1.0);
        }
        acc += mv / 32.0;
    }
    pout[0] = (float)(acc / 3.0);
}

// ---------------- launch ----------------
extern "C" void kernel_launch(void* const* d_in, const int* in_sizes, int n_in,
                              void* d_out, int out_size, void* d_ws, size_t ws_size,
                              hipStream_t stream) {
    const float* x    = (const float*)d_in[0];
    const float* ipw  = (const float*)d_in[1];
    const float* cw   = (const float*)d_in[2];
    const float* cbv  = (const float*)d_in[3];
    const float* xpw  = (const float*)d_in[4];
    const float* dtw  = (const float*)d_in[5];
    const float* dtb  = (const float*)d_in[6];
    const float* Alog = (const float*)d_in[7];
    const float* Dp   = (const float*)d_in[8];
    const float* nw   = (const float*)d_in[9];
    const float* opw  = (const float*)d_in[10];
    const float* ww   = (const float*)d_in[11];
    const float* wb   = (const float*)d_in[12];
    const float* gw   = (const float*)d_in[13];
    const float* gb   = (const float*)d_in[14];
    const float* dw   = (const float*)d_in[15];
    const float* dbp  = (const float*)d_in[16];
    const float* bp   = (const float*)d_in[17];

    float* ws   = (float*)d_ws;
    float* z    = ws + OFF_Z;
    float* xin  = ws + OFF_XIN;
    float* h    = ws + OFF_H;
    float* xc   = ws + OFF_XC;
    float* yb   = ((size_t)WS_NEED <= ws_size) ? (ws + OFF_YB) : xc;
    float* Ap   = ws + OFF_AP;
    float* Sv   = ws + OFF_SV;
    float* raw  = ws + OFF_RAW;    // aliases Ap region (dead by then)
    float* smo  = ws + OFF_SMO;
    double* part = (double*)(ws + OFF_PART);
    float* dout = (float*)d_out;

    hipLaunchKernelGGL(k_prep, dim3(1023), dim3(256), 0, stream, x, z, xin);
    for (int l = 0; l < NLn; l++) {
        const float* hin = (l == 0) ? xin : h;
        long mstride = (l == 0) ? 0L : 4*N_BL;
        hipLaunchKernelGGL(k_preconv, dim3(3069), dim3(256), 0, stream,
                           hin, mstride, l, ipw, cw, cbv, nw, xc);
        hipLaunchKernelGGL(k_scanB, dim3(3072), dim3(256), 0, stream,
                           xc, l, xpw, dtw, dtb, Alog, Ap, Sv);
        hipLaunchKernelGGL(k_scanC, dim3(24), dim3(256), 0, stream, Ap, Sv);
        hipLaunchKernelGGL(k_scanD, dim3(3072), dim3(256), 0, stream,
                           xc, yb, l, xpw, dtw, dtb, Alog, Sv, Dp);
        hipLaunchKernelGGL(k_post, dim3(3069), dim3(256), 0, stream,
                           hin, mstride, h, yb, l, ipw, nw, opw);
    }
    hipLaunchKernelGGL(k_head, dim3(1023), dim3(256), 0, stream,
                       h, ww, wb, gw, gb, dw, dbp, raw, dout);
    hipLaunchKernelGGL(k_smooth, dim3(1023), dim3(256), 0, stream,
                       raw, z, bp, smo, dout);
    hipLaunchKernelGGL(k_pen1, dim3(96), dim3(256), 0, stream, smo, part);
    hipLaunchKernelGGL(k_pen2, dim3(1), dim3(64), 0, stream, part, dout + 13*N_BL);
}

// Round 6
// 290.123 us; speedup vs baseline: 4.9883x; 1.2312x over previous
//
#include <hip/hip_runtime.h>
#include <math.h>

// ---------------- problem constants ----------------
#define Bn_   32
#define Ln_   8192
#define LCn   8184            // L - 8
#define NLn   2
#define NCHn  85              // scan chunks (85*96 waves = 8160 = 2040 blocks -> all resident)
#define CHn   97              // chunk length (last chunk = 36)

static constexpr long N_BL = (long)Bn_ * LCn;            // 261888
static constexpr long NCARRY = 3L * Bn_ * NCHn * 64;     // 522240

// ---- ws layout (float offsets), total 48N = 50.28 MB ----
static constexpr long OFF_H    = 0;                  // 12N  (mamba hidden)
static constexpr long OFF_REC  = 12*N_BL;            // 24N  (rec = [u0..3, lg0..3] per (m,b,t))
static constexpr long OFF_YB   = 36*N_BL;            // 12N  (scan output y)
// aliases over REC (dead after post l=1):
static constexpr long OFF_RAW  = OFF_REC;            // 3N
static constexpr long OFF_SMO  = OFF_REC + 3*N_BL;   // 3N
static constexpr long OFF_PART = OFF_REC + 6*N_BL;   // 384 floats (192 doubles)

// ---- d_out scratch layout (float offsets; dead before head/smooth overwrite) ----
// XIN at [0, 4N)   -- written by prep, last read by post l=0
// AP  at [4N, 4N+NCARRY), SV after -- last read by scanD l=1
// d_out real outputs: yhat [0,N) (smooth), controls [N,13N) (head), penalty [13N] (pen2)

#define L2E_  1.4426950408889634f     // log2(e)
#define LN2_  0.6931471805599453f     // ln(2)
#define EXP2_(x) __builtin_amdgcn_exp2f(x)
#define LOG2_(x) __builtin_amdgcn_logf(x)

// fast silu: v / (1 + e^{-v})
__device__ __forceinline__ float si_(float v) {
    float e = EXP2_(-v * L2E_);
    return v * __builtin_amdgcn_rcpf(1.f + e);
}

// sum over the 16-lane row (n-group) via DPP rotate-adds; result in all 16 lanes
__device__ __forceinline__ float rowsum16(float p) {
    p += __int_as_float(__builtin_amdgcn_update_dpp(0, __float_as_int(p), 0x128, 0xF, 0xF, true)); // row_ror:8
    p += __int_as_float(__builtin_amdgcn_update_dpp(0, __float_as_int(p), 0x124, 0xF, 0xF, true)); // row_ror:4
    p += __int_as_float(__builtin_amdgcn_update_dpp(0, __float_as_int(p), 0x122, 0xF, 0xF, true)); // row_ror:2
    p += __int_as_float(__builtin_amdgcn_update_dpp(0, __float_as_int(p), 0x121, 0xF, 0xF, true)); // row_ror:1
    return p;
}

// ---------------- 1. deriv + x_in (xin lives in d_out scratch) ----------------
__global__ void k_prep(const float* __restrict__ x, float* __restrict__ xin) {
    long idx = (long)blockIdx.x * 256 + threadIdx.x;
    if (idx >= N_BL) return;
    int b = (int)(idx / LCn);
    int t = (int)(idx - (long)b * LCn);
    const float* xb = x + (long)b * Ln_;
    const float c0 = 1.f/280.f, c1 = -4.f/105.f, c2 = 0.2f, c3 = -0.8f,
                c5 = 0.8f, c6 = -0.2f, c7 = 4.f/105.f, c8 = -1.f/280.f;
    float xd  = c0*xb[t]   + c1*xb[t+1] + c2*xb[t+2] + c3*xb[t+3]
              + c5*xb[t+5] + c6*xb[t+6] + c7*xb[t+7] + c8*xb[t+8];
    float z0  = xb[t+4];
    int tf = LCn - 1 - t;
    float xdf = c0*xb[tf]   + c1*xb[tf+1] + c2*xb[tf+2] + c3*xb[tf+3]
              + c5*xb[tf+5] + c6*xb[tf+6] + c7*xb[tf+7] + c8*xb[tf+8];
    float zf0 = xb[tf+4];
    float4 v; v.x = z0; v.y = xd; v.z = zf0; v.w = xdf;
    *(float4*)(xin + idx*4) = v;
}

// ---------------- 2. rmsnorm + in_proj + conv + silu + lg precompute ----------------
__global__ void k_preconv(const float* __restrict__ hin, long mstride, int l,
                          const float* __restrict__ ipw, const float* __restrict__ cw,
                          const float* __restrict__ cbv, const float* __restrict__ nw,
                          const float* __restrict__ xpw, const float* __restrict__ dtw,
                          const float* __restrict__ dtb, float* __restrict__ rec) {
    long idx = (long)blockIdx.x * 256 + threadIdx.x;
    if (idx >= 3*N_BL) return;
    int m = (int)(idx / N_BL);
    long r = idx - (long)m * N_BL;
    int bb = (int)(r / LCn);
    int t  = (int)(r - (long)bb * LCn);
    int ml = m*NLn + l;
    const float* hb = hin + (long)m*mstride + (long)bb*LCn*4;
    const float* W  = ipw + (long)ml*32;
    const float* wn = nw  + ml*4;
    const float* wc = cw  + ml*16;
    const float* bc = cbv + ml*4;
    float acc0=0.f, acc1=0.f, acc2=0.f, acc3=0.f;
#pragma unroll
    for (int j = 0; j < 4; j++) {
        int tt = t - 3 + j;
        if (tt < 0) continue;
        float4 hv = *(const float4*)(hb + (long)tt*4);
        float ms = (hv.x*hv.x + hv.y*hv.y + hv.z*hv.z + hv.w*hv.w)*0.25f + 1e-5f;
        float rs = __builtin_amdgcn_rsqf(ms);
        float hn0 = hv.x*rs*wn[0], hn1 = hv.y*rs*wn[1];
        float hn2 = hv.z*rs*wn[2], hn3 = hv.w*rs*wn[3];
        float x0 = W[0]*hn0 + W[1]*hn1 + W[2]*hn2 + W[3]*hn3;
        float x1 = W[4]*hn0 + W[5]*hn1 + W[6]*hn2 + W[7]*hn3;
        float x2 = W[8]*hn0 + W[9]*hn1 + W[10]*hn2 + W[11]*hn3;
        float x3 = W[12]*hn0 + W[13]*hn1 + W[14]*hn2 + W[15]*hn3;
        acc0 = fmaf(x0, wc[0*4+j], acc0);
        acc1 = fmaf(x1, wc[1*4+j], acc1);
        acc2 = fmaf(x2, wc[2*4+j], acc2);
        acc3 = fmaf(x3, wc[3*4+j], acc3);
    }
    float4 o;
    o.x = si_(acc0 + bc[0]); o.y = si_(acc1 + bc[1]);
    o.z = si_(acc2 + bc[2]); o.w = si_(acc3 + bc[3]);
    // lg[d] = log2(1 + exp(dtr*dtw_d + dtb_d))  (softplus in log2 space)
    const float* P = xpw + (long)ml*33*4;
    float dtr = o.x*P[0] + o.y*P[1] + o.z*P[2] + o.w*P[3];
    const float* dwv = dtw + ml*4;
    const float* dbv = dtb + ml*4;
    float4 lg;
    lg.x = LOG2_(1.f + EXP2_(fmaf(dtr, dwv[0], dbv[0]) * L2E_));
    lg.y = LOG2_(1.f + EXP2_(fmaf(dtr, dwv[1], dbv[1]) * L2E_));
    lg.z = LOG2_(1.f + EXP2_(fmaf(dtr, dwv[2], dbv[2]) * L2E_));
    lg.w = LOG2_(1.f + EXP2_(fmaf(dtr, dwv[3], dbv[3]) * L2E_));
    float* rp = rec + ((long)m*N_BL + r)*8;
    *(float4*)rp       = o;
    *(float4*)(rp + 4) = lg;
}

// ---------------- 3a. scan phase B: per-chunk carries ----------------
__global__ __launch_bounds__(256, 8)
void k_scanB(const float* __restrict__ rec, int l,
             const float* __restrict__ xpw, const float* __restrict__ Alog,
             float* __restrict__ Ap, float* __restrict__ Sv) {
    int wid  = (int)(((long)blockIdx.x * 256 + threadIdx.x) >> 6);
    int lane = threadIdx.x & 63;
    int chunk = wid % NCHn;
    int mb    = wid / NCHn;
    int bb = mb & 31, m = mb >> 5;
    int d = lane >> 4, n = lane & 15;
    int ml = m*NLn + l;
    const float* P  = xpw + (long)ml*33*4;
    const float* PB = P + (1+n)*4;
    float pb0 = PB[0]*LN2_, pb1 = PB[1]*LN2_, pb2 = PB[2]*LN2_, pb3 = PB[3]*LN2_;
    float Av  = -EXP2_(Alog[((long)ml*4 + d)*16 + n] * L2E_);   // A (<0); a = exp2(lg*A)
    const float* rb = rec + ((long)m*N_BL + (long)bb*LCn)*8;
    int t0 = chunk*CHn, t1 = min(t0 + CHn, LCn);
    float ap = 1.f, s = 0.f;
#pragma unroll 4
    for (int t = t0; t < t1; t++) {
        const float* rt = rb + (long)t*8;
        float4 u  = *(const float4*)rt;
        float ud  = rt[d];
        float lgd = rt[4+d];
        float a  = EXP2_(lgd * Av);
        float Bv = u.x*pb0 + u.y*pb1 + u.z*pb2 + u.w*pb3;   // delta folded via LN2 in pb
        float w  = (lgd * ud) * Bv;
        ap *= a;
        s = fmaf(a, s, w);
    }
    long ci = ((long)mb*NCHn + chunk)*64 + lane;
    Ap[ci] = ap; Sv[ci] = s;
}

// ---------------- 3b. scan phase C: carries -> exclusive prefix h0 (in place over Sv) ----------------
__global__ void k_scanC(const float* __restrict__ Ap, float* __restrict__ Sv) {
    int wid  = (int)(((long)blockIdx.x * 256 + threadIdx.x) >> 6);
    int lane = threadIdx.x & 63;
    long base = ((long)wid*NCHn)*64 + lane;
    float h = 0.f;
#pragma unroll 8
    for (int cc = 0; cc < NCHn; cc++) {
        long ci = base + (long)cc*64;
        float a = Ap[ci];
        float s = Sv[ci];
        Sv[ci] = h;               // exclusive prefix: h0 for chunk cc
        h = fmaf(a, h, s);
    }
}

// ---------------- 3c. scan phase D: final scan + y ----------------
__global__ __launch_bounds__(256, 8)
void k_scanD(const float* __restrict__ rec, float* __restrict__ yb, int l,
             const float* __restrict__ xpw, const float* __restrict__ Alog,
             const float* __restrict__ H0) {
    int wid  = (int)(((long)blockIdx.x * 256 + threadIdx.x) >> 6);
    int lane = threadIdx.x & 63;
    int chunk = wid % NCHn;
    int mb    = wid / NCHn;
    int bb = mb & 31, m = mb >> 5;
    int d = lane >> 4, n = lane & 15;
    int ml = m*NLn + l;
    const float* P  = xpw + (long)ml*33*4;
    const float* PB = P + (1+n)*4;
    float pb0 = PB[0]*LN2_, pb1 = PB[1]*LN2_, pb2 = PB[2]*LN2_, pb3 = PB[3]*LN2_;
    const float* PC = P + (17+n)*4;
    float pc0 = PC[0], pc1 = PC[1], pc2 = PC[2], pc3 = PC[3];
    float Av  = -EXP2_(Alog[((long)ml*4 + d)*16 + n] * L2E_);
    float hreg = H0[((long)mb*NCHn + chunk)*64 + lane];
    const float* rb = rec + ((long)m*N_BL + (long)bb*LCn)*8;
    float* ybm = yb + ((long)m*N_BL + (long)bb*LCn)*4;
    int t0 = chunk*CHn, t1 = min(t0 + CHn, LCn);
#pragma unroll 4
    for (int t = t0; t < t1; t++) {
        const float* rt = rb + (long)t*8;
        float4 u  = *(const float4*)rt;
        float ud  = rt[d];
        float lgd = rt[4+d];
        float a  = EXP2_(lgd * Av);
        float Bv = u.x*pb0 + u.y*pb1 + u.z*pb2 + u.w*pb3;
        float w  = (lgd * ud) * Bv;
        hreg = fmaf(a, hreg, w);
        float Cv = u.x*pc0 + u.y*pc1 + u.z*pc2 + u.w*pc3;
        float p  = rowsum16(hreg * Cv);
        if (n == 0) ybm[(long)t*4 + d] = p;    // D-term added in k_post
    }
}

// ---------------- 4. gate + out_proj + residual (+ u*D term) ----------------
__global__ void k_post(const float* __restrict__ hin, long mstride,
                       float* __restrict__ h, const float* __restrict__ yb,
                       const float* __restrict__ rec, int l,
                       const float* __restrict__ ipw, const float* __restrict__ nw,
                       const float* __restrict__ opw, const float* __restrict__ Dp) {
    long idx = (long)blockIdx.x * 256 + threadIdx.x;
    if (idx >= 3*N_BL) return;
    int m = (int)(idx / N_BL);
    long r = idx - (long)m * N_BL;
    int ml = m*NLn + l;
    float4 hv = *(const float4*)(hin + (long)m*mstride + r*4);
    float ms = (hv.x*hv.x + hv.y*hv.y + hv.z*hv.z + hv.w*hv.w)*0.25f + 1e-5f;
    float rs = __builtin_amdgcn_rsqf(ms);
    const float* wn = nw + ml*4;
    float hn0 = hv.x*rs*wn[0], hn1 = hv.y*rs*wn[1];
    float hn2 = hv.z*rs*wn[2], hn3 = hv.w*rs*wn[3];
    const float* W = ipw + (long)(ml*8 + 4)*4;
    float4 yv = *(const float4*)(yb + ((long)m*N_BL + r)*4);
    float4 uv = *(const float4*)(rec + ((long)m*N_BL + r)*8);
    const float* Dd = Dp + ml*4;
    yv.x = fmaf(uv.x, Dd[0], yv.x);
    yv.y = fmaf(uv.y, Dd[1], yv.y);
    yv.z = fmaf(uv.z, Dd[2], yv.z);
    yv.w = fmaf(uv.w, Dd[3], yv.w);
    float g0 = yv.x * si_(W[0]*hn0  + W[1]*hn1  + W[2]*hn2  + W[3]*hn3);
    float g1 = yv.y * si_(W[4]*hn0  + W[5]*hn1  + W[6]*hn2  + W[7]*hn3);
    float g2 = yv.z * si_(W[8]*hn0  + W[9]*hn1  + W[10]*hn2 + W[11]*hn3);
    float g3 = yv.w * si_(W[12]*hn0 + W[13]*hn1 + W[14]*hn2 + W[15]*hn3);
    const float* O = opw + ml*16;
    float4 o;
    o.x = O[0]*g0  + O[1]*g1  + O[2]*g2  + O[3]*g3  + hv.x;
    o.y = O[4]*g0  + O[5]*g1  + O[6]*g2  + O[7]*g3  + hv.y;
    o.z = O[8]*g0  + O[9]*g1  + O[10]*g2 + O[11]*g3 + hv.z;
    o.w = O[12]*g0 + O[13]*g1 + O[14]*g2 + O[15]*g3 + hv.w;
    *(float4*)(h + (long)m*4*N_BL + r*4) = o;
}

// ---------------- 5. head: controls + raw omega/gamma/d ----------------
__global__ void k_head(const float* __restrict__ h,
                       const float* __restrict__ ww, const float* __restrict__ wb,
                       const float* __restrict__ gw, const float* __restrict__ gb,
                       const float* __restrict__ dw, const float* __restrict__ dbp,
                       float* __restrict__ raw, float* __restrict__ dout) {
    long idx = (long)blockIdx.x * 256 + threadIdx.x;
    if (idx >= N_BL) return;
    float4 h0 = *(const float4*)(h + idx*4);
    float4 h1 = *(const float4*)(h + 4*N_BL + idx*4);
    float4 h2 = *(const float4*)(h + 8*N_BL + idx*4);
    float4* c = (float4*)(dout + N_BL + idx*12);
    c[0] = h0; c[1] = h1; c[2] = h2;
    raw[idx]          = h0.x*ww[0] + h0.y*ww[1] + h0.z*ww[2] + h0.w*ww[3] + wb[0];
    raw[N_BL + idx]   = (h1.x*gw[0] + h1.y*gw[1] + h1.z*gw[2] + h1.w*gw[3] + gb[0]) / 1000.0f;
    raw[2*N_BL + idx] = fmaxf(h2.x*dw[0] + h2.y*dw[1] + h2.z*dw[2] + h2.w*dw[3] + dbp[0], 0.f);
}

// ---------------- 6. smooth (10-tap, zero-padded) + yhat (z recomputed from x) ----------------
__global__ void k_smooth(const float* __restrict__ x, const float* __restrict__ raw,
                         const float* __restrict__ bp, float* __restrict__ smo,
                         float* __restrict__ dout) {
    long idx = (long)blockIdx.x * 256 + threadIdx.x;
    if (idx >= N_BL) return;
    int b = (int)(idx / LCn);
    int t = (int)(idx - (long)b * LCn);
    const float* ro = raw + (long)b*LCn;
    const float* rg = raw + N_BL   + (long)b*LCn;
    const float* rd = raw + 2*N_BL + (long)b*LCn;
    float so = 0.f, sg = 0.f, sd = 0.f;
    int lo = max(t - 4, 0), hi = min(t + 5, LCn - 1);
    for (int tt = lo; tt <= hi; tt++) {
        so += fabsf(ro[tt]);
        sg += rg[tt];
        sd += fabsf(rd[tt]);
    }
    so *= 0.1f; sg *= 0.1f; sd *= 0.1f;
    smo[idx]          = so;
    smo[N_BL + idx]   = sg;
    smo[2*N_BL + idx] = sd;
    const float* xb = x + (long)b * Ln_;
    const float c0 = 1.f/280.f, c1 = -4.f/105.f, c2 = 0.2f, c3 = -0.8f,
                c5 = 0.8f, c6 = -0.2f, c7 = 4.f/105.f, c8 = -1.f/280.f;
    float xd  = c0*xb[t]   + c1*xb[t+1] + c2*xb[t+2] + c3*xb[t+3]
              + c5*xb[t+5] + c6*xb[t+6] + c7*xb[t+7] + c8*xb[t+8];
    float z1 = xb[t+4];
    float z2 = xd / 0.0001f;
    float bq = fmaxf(bp[0], 0.f) / 1000.0f;
    dout[idx] = -so*so*z1 + sg*z2 - bq*z1*z1*z2 - sd;
}

// ---------------- 7. penalty ----------------
__global__ void k_pen1(const float* __restrict__ smo, double* __restrict__ part) {
    int which = blockIdx.x >> 5;
    int bb    = blockIdx.x & 31;
    const float* s = smo + (long)which*N_BL + (long)bb*LCn;
    double sum = 0.0, sum2 = 0.0;
    for (int t = 1 + threadIdx.x; t < LCn - 1; t += 256) {
        double g = (double)s[t+1] - (double)s[t];
        sum += g; sum2 += g*g;
    }
    __shared__ double s1[256], s2[256];
    s1[threadIdx.x] = sum; s2[threadIdx.x] = sum2;
    __syncthreads();
    for (int o = 128; o > 0; o >>= 1) {
        if ((int)threadIdx.x < o) {
            s1[threadIdx.x] += s1[threadIdx.x + o];
            s2[threadIdx.x] += s2[threadIdx.x + o];
        }
        __syncthreads();
    }
    if (threadIdx.x == 0) {
        part[blockIdx.x*2]     = s1[0];
        part[blockIdx.x*2 + 1] = s2[0];
    }
}

__global__ void k_pen2(const double* __restrict__ part, float* __restrict__ pout) {
    if (threadIdx.x || blockIdx.x) return;
    const double N = (double)(LCn - 2);
    double acc = 0.0;
    for (int w = 0; w < 3; w++) {
        double mv = 0.0;
        for (int bb = 0; bb < 32; bb++) {
            double su  = part[((long)w*32 + bb)*2];
            double s2v = part[((long)w*32 + bb)*2 + 1];
            mv += (s2v - su*su/N) / (N - 1.0);
        }
        acc += mv / 32.0;
    }
    pout[0] = (float)(acc / 3.0);
}

// ---------------- launch ----------------
extern "C" void kernel_launch(void* const* d_in, const int* in_sizes, int n_in,
                              void* d_out, int out_size, void* d_ws, size_t ws_size,
                              hipStream_t stream) {
    const float* x    = (const float*)d_in[0];
    const float* ipw  = (const float*)d_in[1];
    const float* cw   = (const float*)d_in[2];
    const float* cbv  = (const float*)d_in[3];
    const float* xpw  = (const float*)d_in[4];
    const float* dtw  = (const float*)d_in[5];
    const float* dtb  = (const float*)d_in[6];
    const float* Alog = (const float*)d_in[7];
    const float* Dp   = (const float*)d_in[8];
    const float* nw   = (const float*)d_in[9];
    const float* opw  = (const float*)d_in[10];
    const float* ww   = (const float*)d_in[11];
    const float* wb   = (const float*)d_in[12];
    const float* gw   = (const float*)d_in[13];
    const float* gb   = (const float*)d_in[14];
    const float* dw   = (const float*)d_in[15];
    const float* dbp  = (const float*)d_in[16];
    const float* bp   = (const float*)d_in[17];

    float* ws   = (float*)d_ws;
    float* h    = ws + OFF_H;
    float* rec  = ws + OFF_REC;
    float* yb   = ws + OFF_YB;
    float* raw  = ws + OFF_RAW;    // aliases rec (dead after post l=1)
    float* smo  = ws + OFF_SMO;
    double* part = (double*)(ws + OFF_PART);
    float* dout = (float*)d_out;
    // d_out scratch (overwritten by head/smooth/pen2 at the end):
    float* xin = dout;                       // 4N, dead after post l=0
    float* ap  = dout + 4*N_BL;              // NCARRY, dead after scanC l=1
    float* sv  = ap + NCARRY;                // NCARRY, dead after scanD l=1

    hipLaunchKernelGGL(k_prep, dim3(1023), dim3(256), 0, stream, x, xin);
    for (int l = 0; l < NLn; l++) {
        const float* hin = (l == 0) ? xin : h;
        long mstride = (l == 0) ? 0L : 4*N_BL;
        hipLaunchKernelGGL(k_preconv, dim3(3069), dim3(256), 0, stream,
                           hin, mstride, l, ipw, cw, cbv, nw, xpw, dtw, dtb, rec);
        hipLaunchKernelGGL(k_scanB, dim3(2040), dim3(256), 0, stream,
                           rec, l, xpw, Alog, ap, sv);
        hipLaunchKernelGGL(k_scanC, dim3(24), dim3(256), 0, stream, ap, sv);
        hipLaunchKernelGGL(k_scanD, dim3(2040), dim3(256), 0, stream,
                           rec, yb, l, xpw, Alog, sv);
        hipLaunchKernelGGL(k_post, dim3(3069), dim3(256), 0, stream,
                           hin, mstride, h, yb, rec, l, ipw, nw, opw, Dp);
    }
    hipLaunchKernelGGL(k_head, dim3(1023), dim3(256), 0, stream,
                       h, ww, wb, gw, gb, dw, dbp, raw, dout);
    hipLaunchKernelGGL(k_smooth, dim3(1023), dim3(256), 0, stream,
                       x, raw, bp, smo, dout);
    hipLaunchKernelGGL(k_pen1, dim3(96), dim3(256), 0, stream, smo, part);
    hipLaunchKernelGGL(k_pen2, dim3(1), dim3(64), 0, stream, part, dout + 13*N_BL);
}